// Round 1
// baseline (683.849 us; speedup 1.0000x reference)
//
#include <hip/hip_runtime.h>

#define N_NODES 50000
#define N_EDGES 640000
#define N_GRAPH 1024
#define D 128
#define RD 200

static __device__ __forceinline__ int lbound(const int* a, int n, int v) {
  int lo = 0, hi = n;
  while (lo < hi) { int m = (lo + hi) >> 1; if (a[m] < v) lo = m + 1; else hi = m; }
  return lo;
}

// x[n][d] = sum_f atom_emb[f][x_feat[n][f]][d]
__global__ void k_atom(const int* __restrict__ xf, const float* __restrict__ emb,
                       float* __restrict__ x) {
  int t = blockIdx.x * blockDim.x + threadIdx.x;
  if (t >= N_NODES * 32) return;
  int node = t >> 5, c = (t & 31) << 2;
  float a0 = 0.f, a1 = 0.f, a2 = 0.f, a3 = 0.f;
#pragma unroll
  for (int f = 0; f < 9; ++f) {
    int v = xf[node * 9 + f];
    float4 e4 = *(const float4*)&emb[(f * 64 + v) * D + c];
    a0 += e4.x; a1 += e4.y; a2 += e4.z; a3 += e4.w;
  }
  float4 o; o.x = a0; o.y = a1; o.z = a2; o.w = a3;
  *(float4*)&x[node * D + c] = o;
}

__global__ void k_zero(int* __restrict__ p, int n) {
  int t = blockIdx.x * blockDim.x + threadIdx.x;
  if (t < n) p[t] = 0;
}

__global__ void k_count(const int* __restrict__ ei, int* __restrict__ deg) {
  int e = blockIdx.x * blockDim.x + threadIdx.x;
  if (e < N_EDGES) atomicAdd(&deg[ei[N_EDGES + e]], 1);
}

// local exclusive scan per 1024-block; bsum[b] = block total
__global__ void k_scan_blocks(const int* __restrict__ deg, int* __restrict__ excl,
                              int* __restrict__ bsum) {
  __shared__ int sd[1024];
  int i = blockIdx.x * 1024 + threadIdx.x;
  int v = (i < N_NODES) ? deg[i] : 0;
  sd[threadIdx.x] = v;
  __syncthreads();
  for (int off = 1; off < 1024; off <<= 1) {
    int t = (threadIdx.x >= (unsigned)off) ? sd[threadIdx.x - off] : 0;
    __syncthreads();
    sd[threadIdx.x] += t;
    __syncthreads();
  }
  if (i < N_NODES) excl[i] = sd[threadIdx.x] - v;
  if (threadIdx.x == 1023) bsum[blockIdx.x] = sd[1023];
}

// single-wave exclusive scan of block sums (nb <= 64); row_ptr[N] = total
__global__ void k_scan_bsums(int* __restrict__ bsum, int nb, int* __restrict__ row_ptr) {
  int lane = threadIdx.x;
  int v = (lane < nb) ? bsum[lane] : 0;
  int orig = v;
#pragma unroll
  for (int off = 1; off < 64; off <<= 1) {
    int t = __shfl_up(v, off);
    if (lane >= off) v += t;
  }
  if (lane < nb) bsum[lane] = v - orig;
  if (lane == 63) row_ptr[N_NODES] = v;
}

__global__ void k_scan_add(int* __restrict__ row_ptr, int* __restrict__ cursor,
                           const int* __restrict__ bsum) {
  int i = blockIdx.x * 1024 + threadIdx.x;
  if (i < N_NODES) {
    int r = row_ptr[i] + bsum[blockIdx.x];
    row_ptr[i] = r;
    cursor[i] = r;
  }
}

__global__ void k_fill(const int* __restrict__ ei, int* __restrict__ cursor,
                       int* __restrict__ csr_src, int* __restrict__ csr_eid) {
  int e = blockIdx.x * blockDim.x + threadIdx.x;
  if (e >= N_EDGES) return;
  int s = ei[e], d = ei[N_EDGES + e];
  int pos = atomicAdd(&cursor[d], 1);
  csr_src[pos] = s;
  csr_eid[pos] = e;
}

// out[i] = x[i] + sum_{j in in(i)} relu(x[src] + bond_emb_sum(eid))
__global__ __launch_bounds__(256) void k_agg(
    const float* __restrict__ x, const int* __restrict__ row_ptr,
    const int* __restrict__ csr_src, const int* __restrict__ csr_eid,
    const int* __restrict__ bondf, const float* __restrict__ bemb,
    float* __restrict__ out) {
  __shared__ float sB[3 * 16 * D];  // 24 KB bond embedding table
  for (int t = threadIdx.x; t < 3 * 16 * D; t += blockDim.x) sB[t] = bemb[t];
  __syncthreads();
  int lane = threadIdx.x & 63;
  int c2 = lane * 2;
  int wid = blockIdx.x * (blockDim.x >> 6) + (threadIdx.x >> 6);
  int nw = gridDim.x * (blockDim.x >> 6);
  for (int i = wid; i < N_NODES; i += nw) {
    float2 xi = *(const float2*)&x[i * D + c2];
    float a0 = xi.x, a1 = xi.y;
    int e0 = row_ptr[i], e1 = row_ptr[i + 1];
    for (int j = e0; j < e1; ++j) {
      int s = csr_src[j], e = csr_eid[j];
      int f0 = bondf[e * 3], f1 = bondf[e * 3 + 1], f2 = bondf[e * 3 + 2];
      float2 xs = *(const float2*)&x[s * D + c2];
      float2 b0 = *(const float2*)&sB[f0 * D + c2];
      float2 b1 = *(const float2*)&sB[(16 + f1) * D + c2];
      float2 b2 = *(const float2*)&sB[(32 + f2) * D + c2];
      float m0 = xs.x + b0.x + b1.x + b2.x;
      float m1 = xs.y + b0.y + b1.y + b2.y;
      a0 += fmaxf(m0, 0.f);
      a1 += fmaxf(m1, 0.f);
    }
    float2 o; o.x = a0; o.y = a1;
    *(float2*)&out[i * D + c2] = o;
  }
}

// O[n][:] = (relu?) (A[n][:] @ W[128][128] + bias)
__global__ __launch_bounds__(256) void k_gemm128(
    const float* __restrict__ A, const float* __restrict__ W,
    const float* __restrict__ bias, float* __restrict__ O, int relu) {
  __shared__ float sA[64][132];
  int base = blockIdx.x * 64;
  for (int t = threadIdx.x; t < 64 * 32; t += 256) {
    int nn = t >> 5, kq = (t & 31) << 2;
    int gi = base + nn;
    float4 v; v.x = 0.f; v.y = 0.f; v.z = 0.f; v.w = 0.f;
    if (gi < N_NODES) v = *(const float4*)&A[gi * D + kq];
    *(float4*)&sA[nn][kq] = v;
  }
  __syncthreads();
  int c = (threadIdx.x & 31) << 2;   // 4 output cols
  int s = (threadIdx.x >> 5) << 3;   // 8 nodes
  float acc[8][4];
#pragma unroll
  for (int i = 0; i < 8; ++i) { acc[i][0] = 0.f; acc[i][1] = 0.f; acc[i][2] = 0.f; acc[i][3] = 0.f; }
  for (int k = 0; k < 128; k += 4) {
    float4 w0 = *(const float4*)&W[(k + 0) * D + c];
    float4 w1 = *(const float4*)&W[(k + 1) * D + c];
    float4 w2 = *(const float4*)&W[(k + 2) * D + c];
    float4 w3 = *(const float4*)&W[(k + 3) * D + c];
#pragma unroll
    for (int i = 0; i < 8; ++i) {
      float4 a4 = *(const float4*)&sA[s + i][k];
      acc[i][0] += a4.x * w0.x + a4.y * w1.x + a4.z * w2.x + a4.w * w3.x;
      acc[i][1] += a4.x * w0.y + a4.y * w1.y + a4.z * w2.y + a4.w * w3.y;
      acc[i][2] += a4.x * w0.z + a4.y * w1.z + a4.z * w2.z + a4.w * w3.z;
      acc[i][3] += a4.x * w0.w + a4.y * w1.w + a4.z * w2.w + a4.w * w3.w;
    }
  }
  float4 b4 = *(const float4*)&bias[c];
#pragma unroll
  for (int i = 0; i < 8; ++i) {
    int gi = base + s + i;
    if (gi < N_NODES) {
      float4 o;
      o.x = acc[i][0] + b4.x; o.y = acc[i][1] + b4.y;
      o.z = acc[i][2] + b4.z; o.w = acc[i][3] + b4.w;
      if (relu) { o.x = fmaxf(o.x, 0.f); o.y = fmaxf(o.y, 0.f); o.z = fmaxf(o.z, 0.f); o.w = fmaxf(o.w, 0.f); }
      *(float4*)&O[gi * D + c] = o;
    }
  }
}

// mean-pool per graph (batch sorted) + concat rdkit -> hcat[G][328]
__global__ __launch_bounds__(256) void k_pool(
    const float* __restrict__ x, const int* __restrict__ batch,
    const float* __restrict__ rdkit, float* __restrict__ hcat) {
  int g = blockIdx.x * 4 + (threadIdx.x >> 6);
  if (g >= N_GRAPH) return;
  int lane = threadIdx.x & 63;
  int lo = lbound(batch, N_NODES, g);
  int hi = lbound(batch, N_NODES, g + 1);
  float a0 = 0.f, a1 = 0.f;
  for (int i = lo; i < hi; ++i) {
    float2 v = *(const float2*)&x[i * D + lane * 2];
    a0 += v.x; a1 += v.y;
  }
  float inv = 1.f / fmaxf((float)(hi - lo), 1.f);
  hcat[g * 328 + lane * 2] = a0 * inv;
  hcat[g * 328 + lane * 2 + 1] = a1 * inv;
  for (int r = lane; r < RD; r += 64)
    hcat[g * 328 + D + r] = rdkit[g * RD + r];
}

// h1 = relu(hcat[1024,328] @ W[328,512] + b)
__global__ __launch_bounds__(512) void k_mlp1(
    const float* __restrict__ A, const float* __restrict__ W,
    const float* __restrict__ B, float* __restrict__ O) {
  __shared__ float sA[8 * 328];
  int gbase = blockIdx.x * 8;
  for (int t = threadIdx.x; t < 8 * 328; t += 512) sA[t] = A[gbase * 328 + t];
  __syncthreads();
  int j = threadIdx.x;
  float acc[8];
#pragma unroll
  for (int i = 0; i < 8; ++i) acc[i] = 0.f;
  for (int k = 0; k < 328; k += 4) {
    float w0 = W[(k + 0) * 512 + j];
    float w1 = W[(k + 1) * 512 + j];
    float w2 = W[(k + 2) * 512 + j];
    float w3 = W[(k + 3) * 512 + j];
#pragma unroll
    for (int i = 0; i < 8; ++i) {
      float4 a = *(const float4*)&sA[i * 328 + k];
      acc[i] += a.x * w0 + a.y * w1 + a.z * w2 + a.w * w3;
    }
  }
  float bj = B[j];
#pragma unroll
  for (int i = 0; i < 8; ++i) O[(gbase + i) * 512 + j] = fmaxf(acc[i] + bj, 0.f);
}

// h2 = relu(h1[1024,512] @ W[512,256] + b)
__global__ __launch_bounds__(256) void k_mlp2(
    const float* __restrict__ A, const float* __restrict__ W,
    const float* __restrict__ B, float* __restrict__ O) {
  __shared__ float sA[8 * 512];
  int gbase = blockIdx.x * 8;
  for (int t = threadIdx.x; t < 8 * 512; t += 256) sA[t] = A[gbase * 512 + t];
  __syncthreads();
  int j = threadIdx.x;
  float acc[8];
#pragma unroll
  for (int i = 0; i < 8; ++i) acc[i] = 0.f;
  for (int k = 0; k < 512; k += 4) {
    float w0 = W[(k + 0) * 256 + j];
    float w1 = W[(k + 1) * 256 + j];
    float w2 = W[(k + 2) * 256 + j];
    float w3 = W[(k + 3) * 256 + j];
#pragma unroll
    for (int i = 0; i < 8; ++i) {
      float4 a = *(const float4*)&sA[i * 512 + k];
      acc[i] += a.x * w0 + a.y * w1 + a.z * w2 + a.w * w3;
    }
  }
  float bj = B[j];
#pragma unroll
  for (int i = 0; i < 8; ++i) O[(gbase + i) * 256 + j] = fmaxf(acc[i] + bj, 0.f);
}

// out = h2[1024,256] @ W[256,1] + b
__global__ __launch_bounds__(64) void k_mlp3(
    const float* __restrict__ A, const float* __restrict__ W,
    const float* __restrict__ B, float* __restrict__ out) {
  int g = blockIdx.x;
  int lane = threadIdx.x;
  float4 a = *(const float4*)&A[g * 256 + lane * 4];
  float4 w = *(const float4*)&W[lane * 4];
  float p = a.x * w.x + a.y * w.y + a.z * w.z + a.w * w.w;
#pragma unroll
  for (int off = 32; off > 0; off >>= 1) p += __shfl_down(p, off);
  if (lane == 0) out[g] = p + B[0];
}

extern "C" void kernel_launch(void* const* d_in, const int* in_sizes, int n_in,
                              void* d_out, int out_size, void* d_ws, size_t ws_size,
                              hipStream_t stream) {
  const int* x_feat = (const int*)d_in[0];
  const int* ei = (const int*)d_in[1];
  const int* bondf = (const int*)d_in[2];
  const int* batch = (const int*)d_in[3];
  const float* rdkit = (const float*)d_in[4];
  const float* atom_emb = (const float*)d_in[5];
  const float* bond_emb = (const float*)d_in[6];
  const float* c1w1 = (const float*)d_in[7];
  const float* c1b1 = (const float*)d_in[8];
  const float* c1w2 = (const float*)d_in[9];
  const float* c1b2 = (const float*)d_in[10];
  const float* c2w1 = (const float*)d_in[11];
  const float* c2b1 = (const float*)d_in[12];
  const float* c2w2 = (const float*)d_in[13];
  const float* c2b2 = (const float*)d_in[14];
  const float* mw1 = (const float*)d_in[15];
  const float* mb1 = (const float*)d_in[16];
  const float* mw2 = (const float*)d_in[17];
  const float* mb2 = (const float*)d_in[18];
  const float* mw3 = (const float*)d_in[19];
  const float* mb3 = (const float*)d_in[20];
  float* out = (float*)d_out;

  char* ws = (char*)d_ws;
  size_t off = 0;
  auto alloc = [&](size_t bytes) {
    void* p = ws + off;
    off += (bytes + 255) & ~(size_t)255;
    return p;
  };
  float* bufA = (float*)alloc((size_t)N_NODES * D * 4);
  float* bufB = (float*)alloc((size_t)N_NODES * D * 4);
  float* bufC = (float*)alloc((size_t)N_NODES * D * 4);
  int* deg = (int*)alloc((size_t)N_NODES * 4);
  int* cursor = (int*)alloc((size_t)N_NODES * 4);
  int* row_ptr = (int*)alloc((size_t)(N_NODES + 1) * 4);
  int* bsum = (int*)alloc(64 * 4);
  int* csr_src = (int*)alloc((size_t)N_EDGES * 4);
  int* csr_eid = (int*)alloc((size_t)N_EDGES * 4);
  float* hcat = (float*)alloc((size_t)N_GRAPH * 328 * 4);
  float* h1 = (float*)alloc((size_t)N_GRAPH * 512 * 4);
  float* h2 = (float*)alloc((size_t)N_GRAPH * 256 * 4);

  // node features
  k_atom<<<(N_NODES * 32 + 255) / 256, 256, 0, stream>>>(x_feat, atom_emb, bufA);

  // CSR build (by dst)
  int nb = (N_NODES + 1023) / 1024;
  k_zero<<<(N_NODES + 255) / 256, 256, 0, stream>>>(deg, N_NODES);
  k_count<<<(N_EDGES + 255) / 256, 256, 0, stream>>>(ei, deg);
  k_scan_blocks<<<nb, 1024, 0, stream>>>(deg, row_ptr, bsum);
  k_scan_bsums<<<1, 64, 0, stream>>>(bsum, nb, row_ptr);
  k_scan_add<<<nb, 1024, 0, stream>>>(row_ptr, cursor, bsum);
  k_fill<<<(N_EDGES + 255) / 256, 256, 0, stream>>>(ei, cursor, csr_src, csr_eid);

  int gtiles = (N_NODES + 63) / 64;
  // conv1
  k_agg<<<1024, 256, 0, stream>>>(bufA, row_ptr, csr_src, csr_eid, bondf, bond_emb, bufB);
  k_gemm128<<<gtiles, 256, 0, stream>>>(bufB, c1w1, c1b1, bufC, 1);
  k_gemm128<<<gtiles, 256, 0, stream>>>(bufC, c1w2, c1b2, bufB, 0);
  // conv2
  k_agg<<<1024, 256, 0, stream>>>(bufB, row_ptr, csr_src, csr_eid, bondf, bond_emb, bufA);
  k_gemm128<<<gtiles, 256, 0, stream>>>(bufA, c2w1, c2b1, bufC, 1);
  k_gemm128<<<gtiles, 256, 0, stream>>>(bufC, c2w2, c2b2, bufA, 0);

  // pool + head MLP
  k_pool<<<N_GRAPH / 4, 256, 0, stream>>>(bufA, batch, rdkit, hcat);
  k_mlp1<<<N_GRAPH / 8, 512, 0, stream>>>(hcat, mw1, mb1, h1);
  k_mlp2<<<N_GRAPH / 8, 256, 0, stream>>>(h1, mw2, mb2, h2);
  k_mlp3<<<N_GRAPH, 64, 0, stream>>>(h2, mw3, mb3, out);

  (void)in_sizes; (void)n_in; (void)out_size; (void)ws_size;
}

// Round 2
// 593.036 us; speedup vs baseline: 1.1531x; 1.1531x over previous
//
#include <hip/hip_runtime.h>

#define N_NODES 50000
#define N_EDGES 640000
#define N_GRAPH 1024
#define D 128
#define RD 200

static __device__ __forceinline__ int lbound(const int* a, int n, int v) {
  int lo = 0, hi = n;
  while (lo < hi) { int m = (lo + hi) >> 1; if (a[m] < v) lo = m + 1; else hi = m; }
  return lo;
}

// x[n][d] = sum_f atom_emb[f][x_feat[n][f]][d]
__global__ void k_atom(const int* __restrict__ xf, const float* __restrict__ emb,
                       float* __restrict__ x) {
  int t = blockIdx.x * blockDim.x + threadIdx.x;
  if (t >= N_NODES * 32) return;
  int node = t >> 5, c = (t & 31) << 2;
  float a0 = 0.f, a1 = 0.f, a2 = 0.f, a3 = 0.f;
#pragma unroll
  for (int f = 0; f < 9; ++f) {
    int v = xf[node * 9 + f];
    float4 e4 = *(const float4*)&emb[(f * 64 + v) * D + c];
    a0 += e4.x; a1 += e4.y; a2 += e4.z; a3 += e4.w;
  }
  float4 o; o.x = a0; o.y = a1; o.z = a2; o.w = a3;
  *(float4*)&x[node * D + c] = o;
}

__global__ void k_zero(int* __restrict__ p, int n) {
  int t = blockIdx.x * blockDim.x + threadIdx.x;
  if (t < n) p[t] = 0;
}

__global__ void k_count(const int* __restrict__ ei, int* __restrict__ deg) {
  int e = blockIdx.x * blockDim.x + threadIdx.x;
  if (e < N_EDGES) atomicAdd(&deg[ei[N_EDGES + e]], 1);
}

// local exclusive scan per 1024-block; bsum[b] = block total
__global__ void k_scan_blocks(const int* __restrict__ deg, int* __restrict__ excl,
                              int* __restrict__ bsum) {
  __shared__ int sd[1024];
  int i = blockIdx.x * 1024 + threadIdx.x;
  int v = (i < N_NODES) ? deg[i] : 0;
  sd[threadIdx.x] = v;
  __syncthreads();
  for (int off = 1; off < 1024; off <<= 1) {
    int t = (threadIdx.x >= (unsigned)off) ? sd[threadIdx.x - off] : 0;
    __syncthreads();
    sd[threadIdx.x] += t;
    __syncthreads();
  }
  if (i < N_NODES) excl[i] = sd[threadIdx.x] - v;
  if (threadIdx.x == 1023) bsum[blockIdx.x] = sd[1023];
}

// single-wave exclusive scan of block sums (nb <= 64); row_ptr[N] = total
__global__ void k_scan_bsums(int* __restrict__ bsum, int nb, int* __restrict__ row_ptr) {
  int lane = threadIdx.x;
  int v = (lane < nb) ? bsum[lane] : 0;
  int orig = v;
#pragma unroll
  for (int off = 1; off < 64; off <<= 1) {
    int t = __shfl_up(v, off);
    if (lane >= off) v += t;
  }
  if (lane < nb) bsum[lane] = v - orig;
  if (lane == 63) row_ptr[N_NODES] = v;
}

__global__ void k_scan_add(int* __restrict__ row_ptr, int* __restrict__ cursor,
                           const int* __restrict__ bsum) {
  int i = blockIdx.x * 1024 + threadIdx.x;
  if (i < N_NODES) {
    int r = row_ptr[i] + bsum[blockIdx.x];
    row_ptr[i] = r;
    cursor[i] = r;
  }
}

__global__ void k_fill(const int* __restrict__ ei, int* __restrict__ cursor,
                       int* __restrict__ csr_src, int* __restrict__ csr_eid) {
  int e = blockIdx.x * blockDim.x + threadIdx.x;
  if (e >= N_EDGES) return;
  int s = ei[e], d = ei[N_EDGES + e];
  int pos = atomicAdd(&cursor[d], 1);
  csr_src[pos] = s;
  csr_eid[pos] = e;
}

// out[i] = x[i] + sum_{j in in(i)} relu(x[src] + bond_emb_sum(eid))
// float4/lane, 32 lanes per edge, two half-waves take alternating edges,
// x2 unroll -> 4 independent gathers in flight per wave.
__global__ __launch_bounds__(256) void k_agg(
    const float* __restrict__ x, const int* __restrict__ row_ptr,
    const int* __restrict__ csr_src, const int* __restrict__ csr_eid,
    const int* __restrict__ bondf, const float* __restrict__ bemb,
    float* __restrict__ out) {
  __shared__ float sB[3 * 16 * D];  // 24 KB bond embedding table
  for (int t = threadIdx.x; t < 3 * 16 * D; t += blockDim.x) sB[t] = bemb[t];
  __syncthreads();
  int lane = threadIdx.x & 63;
  int half = lane >> 5;
  int c4 = (lane & 31) << 2;
  int wid = blockIdx.x * (blockDim.x >> 6) + (threadIdx.x >> 6);
  int nw = gridDim.x * (blockDim.x >> 6);
  for (int i = wid; i < N_NODES; i += nw) {
    float4 acc;  acc.x = 0.f;  acc.y = 0.f;  acc.z = 0.f;  acc.w = 0.f;
    float4 acc2; acc2.x = 0.f; acc2.y = 0.f; acc2.z = 0.f; acc2.w = 0.f;
    int e0 = row_ptr[i], e1 = row_ptr[i + 1];
    int j = e0 + half;
    for (; j + 2 < e1; j += 4) {
      int sa = csr_src[j],     ea = csr_eid[j];
      int sb = csr_src[j + 2], eb = csr_eid[j + 2];
      float4 xa = *(const float4*)&x[sa * D + c4];
      float4 xb = *(const float4*)&x[sb * D + c4];
      int fa0 = bondf[ea * 3], fa1 = bondf[ea * 3 + 1], fa2 = bondf[ea * 3 + 2];
      int fb0 = bondf[eb * 3], fb1 = bondf[eb * 3 + 1], fb2 = bondf[eb * 3 + 2];
      float4 a0 = *(const float4*)&sB[fa0 * D + c4];
      float4 a1 = *(const float4*)&sB[(16 + fa1) * D + c4];
      float4 a2 = *(const float4*)&sB[(32 + fa2) * D + c4];
      float4 b0 = *(const float4*)&sB[fb0 * D + c4];
      float4 b1 = *(const float4*)&sB[(16 + fb1) * D + c4];
      float4 b2 = *(const float4*)&sB[(32 + fb2) * D + c4];
      acc.x  += fmaxf(xa.x + a0.x + a1.x + a2.x, 0.f);
      acc.y  += fmaxf(xa.y + a0.y + a1.y + a2.y, 0.f);
      acc.z  += fmaxf(xa.z + a0.z + a1.z + a2.z, 0.f);
      acc.w  += fmaxf(xa.w + a0.w + a1.w + a2.w, 0.f);
      acc2.x += fmaxf(xb.x + b0.x + b1.x + b2.x, 0.f);
      acc2.y += fmaxf(xb.y + b0.y + b1.y + b2.y, 0.f);
      acc2.z += fmaxf(xb.z + b0.z + b1.z + b2.z, 0.f);
      acc2.w += fmaxf(xb.w + b0.w + b1.w + b2.w, 0.f);
    }
    if (j < e1) {
      int sa = csr_src[j], ea = csr_eid[j];
      float4 xa = *(const float4*)&x[sa * D + c4];
      int fa0 = bondf[ea * 3], fa1 = bondf[ea * 3 + 1], fa2 = bondf[ea * 3 + 2];
      float4 a0 = *(const float4*)&sB[fa0 * D + c4];
      float4 a1 = *(const float4*)&sB[(16 + fa1) * D + c4];
      float4 a2 = *(const float4*)&sB[(32 + fa2) * D + c4];
      acc.x += fmaxf(xa.x + a0.x + a1.x + a2.x, 0.f);
      acc.y += fmaxf(xa.y + a0.y + a1.y + a2.y, 0.f);
      acc.z += fmaxf(xa.z + a0.z + a1.z + a2.z, 0.f);
      acc.w += fmaxf(xa.w + a0.w + a1.w + a2.w, 0.f);
    }
    acc.x += acc2.x; acc.y += acc2.y; acc.z += acc2.z; acc.w += acc2.w;
    // combine the two half-waves
    acc.x += __shfl_xor(acc.x, 32);
    acc.y += __shfl_xor(acc.y, 32);
    acc.z += __shfl_xor(acc.z, 32);
    acc.w += __shfl_xor(acc.w, 32);
    if (half == 0) {
      float4 xi = *(const float4*)&x[i * D + c4];
      float4 o;
      o.x = xi.x + acc.x; o.y = xi.y + acc.y;
      o.z = xi.z + acc.z; o.w = xi.w + acc.w;
      *(float4*)&out[i * D + c4] = o;
    }
  }
}

// O[n][:] = (relu?) (A[n][:] @ W[128][128] + bias)
// W staged in LDS (64 KB) once per block; A rows read via broadcast global
// loads (same address per half-wave -> single request, L1-resident tile).
__global__ __launch_bounds__(256) void k_gemm128(
    const float* __restrict__ A, const float* __restrict__ W,
    const float* __restrict__ bias, float* __restrict__ O, int relu) {
  __shared__ float sW[128 * 128];  // 64 KB
  for (int t = threadIdx.x; t < 128 * 32; t += 256)
    *(float4*)&sW[t * 4] = *(const float4*)&W[t * 4];
  __syncthreads();
  int base = blockIdx.x * 64;
  int c = (threadIdx.x & 31) << 2;   // 4 output cols
  int s = (threadIdx.x >> 5) << 3;   // 8 nodes
  const float* Ap[8];
#pragma unroll
  for (int i = 0; i < 8; ++i) {
    int gi = base + s + i;
    if (gi >= N_NODES) gi = N_NODES - 1;  // clamp; store is guarded
    Ap[i] = A + (size_t)gi * D;
  }
  float acc[8][4];
#pragma unroll
  for (int i = 0; i < 8; ++i) { acc[i][0] = 0.f; acc[i][1] = 0.f; acc[i][2] = 0.f; acc[i][3] = 0.f; }
  for (int k = 0; k < 128; k += 4) {
    float4 w0 = *(const float4*)&sW[(k + 0) * D + c];
    float4 w1 = *(const float4*)&sW[(k + 1) * D + c];
    float4 w2 = *(const float4*)&sW[(k + 2) * D + c];
    float4 w3 = *(const float4*)&sW[(k + 3) * D + c];
#pragma unroll
    for (int i = 0; i < 8; ++i) {
      float4 a4 = *(const float4*)&Ap[i][k];
      acc[i][0] += a4.x * w0.x + a4.y * w1.x + a4.z * w2.x + a4.w * w3.x;
      acc[i][1] += a4.x * w0.y + a4.y * w1.y + a4.z * w2.y + a4.w * w3.y;
      acc[i][2] += a4.x * w0.z + a4.y * w1.z + a4.z * w2.z + a4.w * w3.z;
      acc[i][3] += a4.x * w0.w + a4.y * w1.w + a4.z * w2.w + a4.w * w3.w;
    }
  }
  float4 b4 = *(const float4*)&bias[c];
#pragma unroll
  for (int i = 0; i < 8; ++i) {
    int gi = base + s + i;
    if (gi < N_NODES) {
      float4 o;
      o.x = acc[i][0] + b4.x; o.y = acc[i][1] + b4.y;
      o.z = acc[i][2] + b4.z; o.w = acc[i][3] + b4.w;
      if (relu) { o.x = fmaxf(o.x, 0.f); o.y = fmaxf(o.y, 0.f); o.z = fmaxf(o.z, 0.f); o.w = fmaxf(o.w, 0.f); }
      *(float4*)&O[gi * D + c] = o;
    }
  }
}

// mean-pool per graph (batch sorted) + concat rdkit -> hcat[G][328]
__global__ __launch_bounds__(256) void k_pool(
    const float* __restrict__ x, const int* __restrict__ batch,
    const float* __restrict__ rdkit, float* __restrict__ hcat) {
  int g = blockIdx.x * 4 + (threadIdx.x >> 6);
  if (g >= N_GRAPH) return;
  int lane = threadIdx.x & 63;
  int lo = lbound(batch, N_NODES, g);
  int hi = lbound(batch, N_NODES, g + 1);
  float a0 = 0.f, a1 = 0.f;
  for (int i = lo; i < hi; ++i) {
    float2 v = *(const float2*)&x[i * D + lane * 2];
    a0 += v.x; a1 += v.y;
  }
  float inv = 1.f / fmaxf((float)(hi - lo), 1.f);
  hcat[g * 328 + lane * 2] = a0 * inv;
  hcat[g * 328 + lane * 2 + 1] = a1 * inv;
  for (int r = lane; r < RD; r += 64)
    hcat[g * 328 + D + r] = rdkit[g * RD + r];
}

// h1 = relu(hcat[1024,328] @ W[328,512] + b)
__global__ __launch_bounds__(512) void k_mlp1(
    const float* __restrict__ A, const float* __restrict__ W,
    const float* __restrict__ B, float* __restrict__ O) {
  __shared__ float sA[8 * 328];
  int gbase = blockIdx.x * 8;
  for (int t = threadIdx.x; t < 8 * 328; t += 512) sA[t] = A[gbase * 328 + t];
  __syncthreads();
  int j = threadIdx.x;
  float acc[8];
#pragma unroll
  for (int i = 0; i < 8; ++i) acc[i] = 0.f;
  for (int k = 0; k < 328; k += 4) {
    float w0 = W[(k + 0) * 512 + j];
    float w1 = W[(k + 1) * 512 + j];
    float w2 = W[(k + 2) * 512 + j];
    float w3 = W[(k + 3) * 512 + j];
#pragma unroll
    for (int i = 0; i < 8; ++i) {
      float4 a = *(const float4*)&sA[i * 328 + k];
      acc[i] += a.x * w0 + a.y * w1 + a.z * w2 + a.w * w3;
    }
  }
  float bj = B[j];
#pragma unroll
  for (int i = 0; i < 8; ++i) O[(gbase + i) * 512 + j] = fmaxf(acc[i] + bj, 0.f);
}

// h2 = relu(h1[1024,512] @ W[512,256] + b)
__global__ __launch_bounds__(256) void k_mlp2(
    const float* __restrict__ A, const float* __restrict__ W,
    const float* __restrict__ B, float* __restrict__ O) {
  __shared__ float sA[8 * 512];
  int gbase = blockIdx.x * 8;
  for (int t = threadIdx.x; t < 8 * 512; t += 256) sA[t] = A[gbase * 512 + t];
  __syncthreads();
  int j = threadIdx.x;
  float acc[8];
#pragma unroll
  for (int i = 0; i < 8; ++i) acc[i] = 0.f;
  for (int k = 0; k < 512; k += 4) {
    float w0 = W[(k + 0) * 256 + j];
    float w1 = W[(k + 1) * 256 + j];
    float w2 = W[(k + 2) * 256 + j];
    float w3 = W[(k + 3) * 256 + j];
#pragma unroll
    for (int i = 0; i < 8; ++i) {
      float4 a = *(const float4*)&sA[i * 512 + k];
      acc[i] += a.x * w0 + a.y * w1 + a.z * w2 + a.w * w3;
    }
  }
  float bj = B[j];
#pragma unroll
  for (int i = 0; i < 8; ++i) O[(gbase + i) * 256 + j] = fmaxf(acc[i] + bj, 0.f);
}

// out = h2[1024,256] @ W[256,1] + b
__global__ __launch_bounds__(64) void k_mlp3(
    const float* __restrict__ A, const float* __restrict__ W,
    const float* __restrict__ B, float* __restrict__ out) {
  int g = blockIdx.x;
  int lane = threadIdx.x;
  float4 a = *(const float4*)&A[g * 256 + lane * 4];
  float4 w = *(const float4*)&W[lane * 4];
  float p = a.x * w.x + a.y * w.y + a.z * w.z + a.w * w.w;
#pragma unroll
  for (int off = 32; off > 0; off >>= 1) p += __shfl_down(p, off);
  if (lane == 0) out[g] = p + B[0];
}

extern "C" void kernel_launch(void* const* d_in, const int* in_sizes, int n_in,
                              void* d_out, int out_size, void* d_ws, size_t ws_size,
                              hipStream_t stream) {
  const int* x_feat = (const int*)d_in[0];
  const int* ei = (const int*)d_in[1];
  const int* bondf = (const int*)d_in[2];
  const int* batch = (const int*)d_in[3];
  const float* rdkit = (const float*)d_in[4];
  const float* atom_emb = (const float*)d_in[5];
  const float* bond_emb = (const float*)d_in[6];
  const float* c1w1 = (const float*)d_in[7];
  const float* c1b1 = (const float*)d_in[8];
  const float* c1w2 = (const float*)d_in[9];
  const float* c1b2 = (const float*)d_in[10];
  const float* c2w1 = (const float*)d_in[11];
  const float* c2b1 = (const float*)d_in[12];
  const float* c2w2 = (const float*)d_in[13];
  const float* c2b2 = (const float*)d_in[14];
  const float* mw1 = (const float*)d_in[15];
  const float* mb1 = (const float*)d_in[16];
  const float* mw2 = (const float*)d_in[17];
  const float* mb2 = (const float*)d_in[18];
  const float* mw3 = (const float*)d_in[19];
  const float* mb3 = (const float*)d_in[20];
  float* out = (float*)d_out;

  char* ws = (char*)d_ws;
  size_t off = 0;
  auto alloc = [&](size_t bytes) {
    void* p = ws + off;
    off += (bytes + 255) & ~(size_t)255;
    return p;
  };
  float* bufA = (float*)alloc((size_t)N_NODES * D * 4);
  float* bufB = (float*)alloc((size_t)N_NODES * D * 4);
  float* bufC = (float*)alloc((size_t)N_NODES * D * 4);
  int* deg = (int*)alloc((size_t)N_NODES * 4);
  int* cursor = (int*)alloc((size_t)N_NODES * 4);
  int* row_ptr = (int*)alloc((size_t)(N_NODES + 1) * 4);
  int* bsum = (int*)alloc(64 * 4);
  int* csr_src = (int*)alloc((size_t)N_EDGES * 4);
  int* csr_eid = (int*)alloc((size_t)N_EDGES * 4);
  float* hcat = (float*)alloc((size_t)N_GRAPH * 328 * 4);
  float* h1 = (float*)alloc((size_t)N_GRAPH * 512 * 4);
  float* h2 = (float*)alloc((size_t)N_GRAPH * 256 * 4);

  // node features
  k_atom<<<(N_NODES * 32 + 255) / 256, 256, 0, stream>>>(x_feat, atom_emb, bufA);

  // CSR build (by dst)
  int nb = (N_NODES + 1023) / 1024;
  k_zero<<<(N_NODES + 255) / 256, 256, 0, stream>>>(deg, N_NODES);
  k_count<<<(N_EDGES + 255) / 256, 256, 0, stream>>>(ei, deg);
  k_scan_blocks<<<nb, 1024, 0, stream>>>(deg, row_ptr, bsum);
  k_scan_bsums<<<1, 64, 0, stream>>>(bsum, nb, row_ptr);
  k_scan_add<<<nb, 1024, 0, stream>>>(row_ptr, cursor, bsum);
  k_fill<<<(N_EDGES + 255) / 256, 256, 0, stream>>>(ei, cursor, csr_src, csr_eid);

  int gtiles = (N_NODES + 63) / 64;
  // conv1
  k_agg<<<1536, 256, 0, stream>>>(bufA, row_ptr, csr_src, csr_eid, bondf, bond_emb, bufB);
  k_gemm128<<<gtiles, 256, 0, stream>>>(bufB, c1w1, c1b1, bufC, 1);
  k_gemm128<<<gtiles, 256, 0, stream>>>(bufC, c1w2, c1b2, bufB, 0);
  // conv2
  k_agg<<<1536, 256, 0, stream>>>(bufB, row_ptr, csr_src, csr_eid, bondf, bond_emb, bufA);
  k_gemm128<<<gtiles, 256, 0, stream>>>(bufA, c2w1, c2b1, bufC, 1);
  k_gemm128<<<gtiles, 256, 0, stream>>>(bufC, c2w2, c2b2, bufA, 0);

  // pool + head MLP
  k_pool<<<N_GRAPH / 4, 256, 0, stream>>>(bufA, batch, rdkit, hcat);
  k_mlp1<<<N_GRAPH / 8, 512, 0, stream>>>(hcat, mw1, mb1, h1);
  k_mlp2<<<N_GRAPH / 8, 256, 0, stream>>>(h1, mw2, mb2, h2);
  k_mlp3<<<N_GRAPH, 64, 0, stream>>>(h2, mw3, mb3, out);

  (void)in_sizes; (void)n_in; (void)out_size; (void)ws_size;
}

// Round 3
// 577.594 us; speedup vs baseline: 1.1840x; 1.0267x over previous
//
#include <hip/hip_runtime.h>

#define N_NODES 50000
#define N_EDGES 640000
#define N_GRAPH 1024
#define D 128
#define RD 200

typedef __attribute__((ext_vector_type(8))) short bf16x8;
typedef __attribute__((ext_vector_type(4))) float f32x4;

static __device__ __forceinline__ unsigned short f2bf(float f) {
  unsigned u = __float_as_uint(f);
  unsigned r = (u + 0x7fff + ((u >> 16) & 1)) >> 16;
  return (unsigned short)r;
}

static __device__ __forceinline__ int lbound(const int* a, int n, int v) {
  int lo = 0, hi = n;
  while (lo < hi) { int m = (lo + hi) >> 1; if (a[m] < v) lo = m + 1; else hi = m; }
  return lo;
}

// x[n][d] = sum_f atom_emb[f][x_feat[n][f]][d]
__global__ void k_atom(const int* __restrict__ xf, const float* __restrict__ emb,
                       float* __restrict__ x) {
  int t = blockIdx.x * blockDim.x + threadIdx.x;
  if (t >= N_NODES * 32) return;
  int node = t >> 5, c = (t & 31) << 2;
  float a0 = 0.f, a1 = 0.f, a2 = 0.f, a3 = 0.f;
#pragma unroll
  for (int f = 0; f < 9; ++f) {
    int v = xf[node * 9 + f];
    float4 e4 = *(const float4*)&emb[(f * 64 + v) * D + c];
    a0 += e4.x; a1 += e4.y; a2 += e4.z; a3 += e4.w;
  }
  float4 o; o.x = a0; o.y = a1; o.z = a2; o.w = a3;
  *(float4*)&x[node * D + c] = o;
}

__global__ void k_zero(int* __restrict__ p, int n) {
  int t = blockIdx.x * blockDim.x + threadIdx.x;
  if (t < n) p[t] = 0;
}

__global__ void k_count(const int* __restrict__ ei, int* __restrict__ deg) {
  int e = blockIdx.x * blockDim.x + threadIdx.x;
  if (e < N_EDGES) atomicAdd(&deg[ei[N_EDGES + e]], 1);
}

__global__ void k_scan_blocks(const int* __restrict__ deg, int* __restrict__ excl,
                              int* __restrict__ bsum) {
  __shared__ int sd[1024];
  int i = blockIdx.x * 1024 + threadIdx.x;
  int v = (i < N_NODES) ? deg[i] : 0;
  sd[threadIdx.x] = v;
  __syncthreads();
  for (int off = 1; off < 1024; off <<= 1) {
    int t = (threadIdx.x >= (unsigned)off) ? sd[threadIdx.x - off] : 0;
    __syncthreads();
    sd[threadIdx.x] += t;
    __syncthreads();
  }
  if (i < N_NODES) excl[i] = sd[threadIdx.x] - v;
  if (threadIdx.x == 1023) bsum[blockIdx.x] = sd[1023];
}

__global__ void k_scan_bsums(int* __restrict__ bsum, int nb, int* __restrict__ row_ptr) {
  int lane = threadIdx.x;
  int v = (lane < nb) ? bsum[lane] : 0;
  int orig = v;
#pragma unroll
  for (int off = 1; off < 64; off <<= 1) {
    int t = __shfl_up(v, off);
    if (lane >= off) v += t;
  }
  if (lane < nb) bsum[lane] = v - orig;
  if (lane == 63) row_ptr[N_NODES] = v;
}

__global__ void k_scan_add(int* __restrict__ row_ptr, int* __restrict__ cursor,
                           const int* __restrict__ bsum) {
  int i = blockIdx.x * 1024 + threadIdx.x;
  if (i < N_NODES) {
    int r = row_ptr[i] + bsum[blockIdx.x];
    row_ptr[i] = r;
    cursor[i] = r;
  }
}

__global__ void k_fill(const int* __restrict__ ei, int* __restrict__ cursor,
                       int* __restrict__ csr_src, int* __restrict__ csr_eid) {
  int e = blockIdx.x * blockDim.x + threadIdx.x;
  if (e >= N_EDGES) return;
  int s = ei[e], d = ei[N_EDGES + e];
  int pos = atomicAdd(&cursor[d], 1);
  csr_src[pos] = s;
  csr_eid[pos] = e;
}

// transpose + bf16 hi/lo split of the 4 conv weight matrices
// out layout: [w][n][k] (n = output col, k = input dim)
__global__ void k_prep_w(const float* __restrict__ w0, const float* __restrict__ w1,
                         const float* __restrict__ w2, const float* __restrict__ w3,
                         short* __restrict__ hi, short* __restrict__ lo) {
  const float* W = (blockIdx.y == 0) ? w0 : (blockIdx.y == 1) ? w1
                   : (blockIdx.y == 2) ? w2 : w3;
  int t = blockIdx.x * 256 + threadIdx.x;  // t = n*128 + k
  int n = t >> 7, k = t & 127;
  float v = W[k * D + n];
  unsigned short h = f2bf(v);
  float hf = __uint_as_float((unsigned)h << 16);
  unsigned short l = f2bf(v - hf);
  hi[blockIdx.y * (D * D) + t] = (short)h;
  lo[blockIdx.y * (D * D) + t] = (short)l;
}

// out[i] = x[i] + sum_{j in in(i)} relu(x[src] + bond_emb_sum(eid))
// float4/lane, 32 lanes per edge, half-waves take alternating edges,
// x4 unroll -> 8 independent gathers in flight per wave.
__global__ __launch_bounds__(256) void k_agg(
    const float* __restrict__ x, const int* __restrict__ row_ptr,
    const int* __restrict__ csr_src, const int* __restrict__ csr_eid,
    const int* __restrict__ bondf, const float* __restrict__ bemb,
    float* __restrict__ out) {
  __shared__ float sB[3 * 16 * D];  // 24 KB bond embedding table
  for (int t = threadIdx.x; t < 3 * 16 * D; t += blockDim.x) sB[t] = bemb[t];
  __syncthreads();
  int lane = threadIdx.x & 63;
  int half = lane >> 5;
  int c4 = (lane & 31) << 2;
  int wid = blockIdx.x * (blockDim.x >> 6) + (threadIdx.x >> 6);
  int nw = gridDim.x * (blockDim.x >> 6);
  for (int i = wid; i < N_NODES; i += nw) {
    float4 ac[4];
#pragma unroll
    for (int u = 0; u < 4; ++u) { ac[u].x = 0.f; ac[u].y = 0.f; ac[u].z = 0.f; ac[u].w = 0.f; }
    int e0 = row_ptr[i], e1 = row_ptr[i + 1];
    int j = e0 + half;
    for (; j + 6 < e1; j += 8) {
      int s0 = csr_src[j],     q0 = csr_eid[j];
      int s1 = csr_src[j + 2], q1 = csr_eid[j + 2];
      int s2 = csr_src[j + 4], q2 = csr_eid[j + 4];
      int s3 = csr_src[j + 6], q3 = csr_eid[j + 6];
      float4 x0 = *(const float4*)&x[s0 * D + c4];
      float4 x1 = *(const float4*)&x[s1 * D + c4];
      float4 x2 = *(const float4*)&x[s2 * D + c4];
      float4 x3 = *(const float4*)&x[s3 * D + c4];
      int f00 = bondf[q0 * 3], f01 = bondf[q0 * 3 + 1], f02 = bondf[q0 * 3 + 2];
      int f10 = bondf[q1 * 3], f11 = bondf[q1 * 3 + 1], f12 = bondf[q1 * 3 + 2];
      int f20 = bondf[q2 * 3], f21 = bondf[q2 * 3 + 1], f22 = bondf[q2 * 3 + 2];
      int f30 = bondf[q3 * 3], f31 = bondf[q3 * 3 + 1], f32 = bondf[q3 * 3 + 2];
      {
        float4 b0 = *(const float4*)&sB[f00 * D + c4];
        float4 b1 = *(const float4*)&sB[(16 + f01) * D + c4];
        float4 b2 = *(const float4*)&sB[(32 + f02) * D + c4];
        ac[0].x += fmaxf(x0.x + b0.x + b1.x + b2.x, 0.f);
        ac[0].y += fmaxf(x0.y + b0.y + b1.y + b2.y, 0.f);
        ac[0].z += fmaxf(x0.z + b0.z + b1.z + b2.z, 0.f);
        ac[0].w += fmaxf(x0.w + b0.w + b1.w + b2.w, 0.f);
      }
      {
        float4 b0 = *(const float4*)&sB[f10 * D + c4];
        float4 b1 = *(const float4*)&sB[(16 + f11) * D + c4];
        float4 b2 = *(const float4*)&sB[(32 + f12) * D + c4];
        ac[1].x += fmaxf(x1.x + b0.x + b1.x + b2.x, 0.f);
        ac[1].y += fmaxf(x1.y + b0.y + b1.y + b2.y, 0.f);
        ac[1].z += fmaxf(x1.z + b0.z + b1.z + b2.z, 0.f);
        ac[1].w += fmaxf(x1.w + b0.w + b1.w + b2.w, 0.f);
      }
      {
        float4 b0 = *(const float4*)&sB[f20 * D + c4];
        float4 b1 = *(const float4*)&sB[(16 + f21) * D + c4];
        float4 b2 = *(const float4*)&sB[(32 + f22) * D + c4];
        ac[2].x += fmaxf(x2.x + b0.x + b1.x + b2.x, 0.f);
        ac[2].y += fmaxf(x2.y + b0.y + b1.y + b2.y, 0.f);
        ac[2].z += fmaxf(x2.z + b0.z + b1.z + b2.z, 0.f);
        ac[2].w += fmaxf(x2.w + b0.w + b1.w + b2.w, 0.f);
      }
      {
        float4 b0 = *(const float4*)&sB[f30 * D + c4];
        float4 b1 = *(const float4*)&sB[(16 + f31) * D + c4];
        float4 b2 = *(const float4*)&sB[(32 + f32) * D + c4];
        ac[3].x += fmaxf(x3.x + b0.x + b1.x + b2.x, 0.f);
        ac[3].y += fmaxf(x3.y + b0.y + b1.y + b2.y, 0.f);
        ac[3].z += fmaxf(x3.z + b0.z + b1.z + b2.z, 0.f);
        ac[3].w += fmaxf(x3.w + b0.w + b1.w + b2.w, 0.f);
      }
    }
    for (; j < e1; j += 2) {
      int sa = csr_src[j], ea = csr_eid[j];
      float4 xa = *(const float4*)&x[sa * D + c4];
      int fa0 = bondf[ea * 3], fa1 = bondf[ea * 3 + 1], fa2 = bondf[ea * 3 + 2];
      float4 b0 = *(const float4*)&sB[fa0 * D + c4];
      float4 b1 = *(const float4*)&sB[(16 + fa1) * D + c4];
      float4 b2 = *(const float4*)&sB[(32 + fa2) * D + c4];
      ac[0].x += fmaxf(xa.x + b0.x + b1.x + b2.x, 0.f);
      ac[0].y += fmaxf(xa.y + b0.y + b1.y + b2.y, 0.f);
      ac[0].z += fmaxf(xa.z + b0.z + b1.z + b2.z, 0.f);
      ac[0].w += fmaxf(xa.w + b0.w + b1.w + b2.w, 0.f);
    }
    float4 acc;
    acc.x = (ac[0].x + ac[1].x) + (ac[2].x + ac[3].x);
    acc.y = (ac[0].y + ac[1].y) + (ac[2].y + ac[3].y);
    acc.z = (ac[0].z + ac[1].z) + (ac[2].z + ac[3].z);
    acc.w = (ac[0].w + ac[1].w) + (ac[2].w + ac[3].w);
    acc.x += __shfl_xor(acc.x, 32);
    acc.y += __shfl_xor(acc.y, 32);
    acc.z += __shfl_xor(acc.z, 32);
    acc.w += __shfl_xor(acc.w, 32);
    if (half == 0) {
      float4 xi = *(const float4*)&x[i * D + c4];
      float4 o;
      o.x = xi.x + acc.x; o.y = xi.y + acc.y;
      o.z = xi.z + acc.z; o.w = xi.w + acc.w;
      *(float4*)&out[i * D + c4] = o;
    }
  }
}

// O[n][:] = (relu?)(A[n][:] @ W + bias) via MFMA, W pre-split bf16 hi/lo
// (transposed: Wt[n][k]). fp32 accuracy via hi*hi + hi*lo + lo*hi.
// Each wave: 16 rows x 128 cols. No LDS.
__global__ __launch_bounds__(256) void k_gemm_mfma(
    const float* __restrict__ A, const short* __restrict__ Wt_hi,
    const short* __restrict__ Wt_lo, const float* __restrict__ bias,
    float* __restrict__ O, int relu) {
  int wave = threadIdx.x >> 6;
  int lane = threadIdx.x & 63;
  int m0 = blockIdx.x * 64 + wave * 16;
  int row = m0 + (lane & 15);
  int rc = row < N_NODES ? row : N_NODES - 1;
  int q = lane >> 4;
  // load + split A fragments: lane holds A[m=lane&15][k = kk*32 + q*8 + j]
  bf16x8 ahi[4], alo[4];
  const float* Arow = A + (size_t)rc * D + q * 8;
#pragma unroll
  for (int kk = 0; kk < 4; ++kk) {
    float4 v0 = *(const float4*)(Arow + kk * 32);
    float4 v1 = *(const float4*)(Arow + kk * 32 + 4);
    float vs0 = v0.x, vs1 = v0.y, vs2 = v0.z, vs3 = v0.w;
    float vs4 = v1.x, vs5 = v1.y, vs6 = v1.z, vs7 = v1.w;
#define SPLIT(idx, val)                                        \
    {                                                          \
      unsigned short h = f2bf(val);                            \
      float hf = __uint_as_float((unsigned)h << 16);           \
      ahi[kk][idx] = (short)h;                                 \
      alo[kk][idx] = (short)f2bf((val) - hf);                  \
    }
    SPLIT(0, vs0) SPLIT(1, vs1) SPLIT(2, vs2) SPLIT(3, vs3)
    SPLIT(4, vs4) SPLIT(5, vs5) SPLIT(6, vs6) SPLIT(7, vs7)
#undef SPLIT
  }
  for (int n0 = 0; n0 < 128; n0 += 16) {
    f32x4 acc = {0.f, 0.f, 0.f, 0.f};
    const short* wh = Wt_hi + (n0 + (lane & 15)) * D + q * 8;
    const short* wl = Wt_lo + (n0 + (lane & 15)) * D + q * 8;
#pragma unroll
    for (int kk = 0; kk < 4; ++kk) {
      bf16x8 bh = *(const bf16x8*)(wh + kk * 32);
      bf16x8 bl = *(const bf16x8*)(wl + kk * 32);
      acc = __builtin_amdgcn_mfma_f32_16x16x32_bf16(ahi[kk], bh, acc, 0, 0, 0);
      acc = __builtin_amdgcn_mfma_f32_16x16x32_bf16(ahi[kk], bl, acc, 0, 0, 0);
      acc = __builtin_amdgcn_mfma_f32_16x16x32_bf16(alo[kk], bh, acc, 0, 0, 0);
    }
    int col = n0 + (lane & 15);
    float b = bias[col];
#pragma unroll
    for (int r = 0; r < 4; ++r) {
      int orow = m0 + q * 4 + r;
      if (orow < N_NODES) {
        float v = acc[r] + b;
        if (relu) v = fmaxf(v, 0.f);
        O[(size_t)orow * D + col] = v;
      }
    }
  }
}

// mean-pool per graph (batch sorted) + concat rdkit -> hcat[G][328]
__global__ __launch_bounds__(256) void k_pool(
    const float* __restrict__ x, const int* __restrict__ batch,
    const float* __restrict__ rdkit, float* __restrict__ hcat) {
  int g = blockIdx.x * 4 + (threadIdx.x >> 6);
  if (g >= N_GRAPH) return;
  int lane = threadIdx.x & 63;
  int lo = lbound(batch, N_NODES, g);
  int hi = lbound(batch, N_NODES, g + 1);
  float a0 = 0.f, a1 = 0.f;
  for (int i = lo; i < hi; ++i) {
    float2 v = *(const float2*)&x[i * D + lane * 2];
    a0 += v.x; a1 += v.y;
  }
  float inv = 1.f / fmaxf((float)(hi - lo), 1.f);
  hcat[g * 328 + lane * 2] = a0 * inv;
  hcat[g * 328 + lane * 2 + 1] = a1 * inv;
  for (int r = lane; r < RD; r += 64)
    hcat[g * 328 + D + r] = rdkit[g * RD + r];
}

// h1 = relu(hcat[1024,328] @ W[328,512] + b)
__global__ __launch_bounds__(512) void k_mlp1(
    const float* __restrict__ A, const float* __restrict__ W,
    const float* __restrict__ B, float* __restrict__ O) {
  __shared__ float sA[8 * 328];
  int gbase = blockIdx.x * 8;
  for (int t = threadIdx.x; t < 8 * 328; t += 512) sA[t] = A[gbase * 328 + t];
  __syncthreads();
  int j = threadIdx.x;
  float acc[8];
#pragma unroll
  for (int i = 0; i < 8; ++i) acc[i] = 0.f;
  for (int k = 0; k < 328; k += 4) {
    float w0 = W[(k + 0) * 512 + j];
    float w1 = W[(k + 1) * 512 + j];
    float w2 = W[(k + 2) * 512 + j];
    float w3 = W[(k + 3) * 512 + j];
#pragma unroll
    for (int i = 0; i < 8; ++i) {
      float4 a = *(const float4*)&sA[i * 328 + k];
      acc[i] += a.x * w0 + a.y * w1 + a.z * w2 + a.w * w3;
    }
  }
  float bj = B[j];
#pragma unroll
  for (int i = 0; i < 8; ++i) O[(gbase + i) * 512 + j] = fmaxf(acc[i] + bj, 0.f);
}

// h2 = relu(h1[1024,512] @ W[512,256] + b)
__global__ __launch_bounds__(256) void k_mlp2(
    const float* __restrict__ A, const float* __restrict__ W,
    const float* __restrict__ B, float* __restrict__ O) {
  __shared__ float sA[8 * 512];
  int gbase = blockIdx.x * 8;
  for (int t = threadIdx.x; t < 8 * 512; t += 256) sA[t] = A[gbase * 512 + t];
  __syncthreads();
  int j = threadIdx.x;
  float acc[8];
#pragma unroll
  for (int i = 0; i < 8; ++i) acc[i] = 0.f;
  for (int k = 0; k < 512; k += 4) {
    float w0 = W[(k + 0) * 256 + j];
    float w1 = W[(k + 1) * 256 + j];
    float w2 = W[(k + 2) * 256 + j];
    float w3 = W[(k + 3) * 256 + j];
#pragma unroll
    for (int i = 0; i < 8; ++i) {
      float4 a = *(const float4*)&sA[i * 512 + k];
      acc[i] += a.x * w0 + a.y * w1 + a.z * w2 + a.w * w3;
    }
  }
  float bj = B[j];
#pragma unroll
  for (int i = 0; i < 8; ++i) O[(gbase + i) * 256 + j] = fmaxf(acc[i] + bj, 0.f);
}

// out = h2[1024,256] @ W[256,1] + b
__global__ __launch_bounds__(64) void k_mlp3(
    const float* __restrict__ A, const float* __restrict__ W,
    const float* __restrict__ B, float* __restrict__ out) {
  int g = blockIdx.x;
  int lane = threadIdx.x;
  float4 a = *(const float4*)&A[g * 256 + lane * 4];
  float4 w = *(const float4*)&W[lane * 4];
  float p = a.x * w.x + a.y * w.y + a.z * w.z + a.w * w.w;
#pragma unroll
  for (int off = 32; off > 0; off >>= 1) p += __shfl_down(p, off);
  if (lane == 0) out[g] = p + B[0];
}

extern "C" void kernel_launch(void* const* d_in, const int* in_sizes, int n_in,
                              void* d_out, int out_size, void* d_ws, size_t ws_size,
                              hipStream_t stream) {
  const int* x_feat = (const int*)d_in[0];
  const int* ei = (const int*)d_in[1];
  const int* bondf = (const int*)d_in[2];
  const int* batch = (const int*)d_in[3];
  const float* rdkit = (const float*)d_in[4];
  const float* atom_emb = (const float*)d_in[5];
  const float* bond_emb = (const float*)d_in[6];
  const float* c1w1 = (const float*)d_in[7];
  const float* c1b1 = (const float*)d_in[8];
  const float* c1w2 = (const float*)d_in[9];
  const float* c1b2 = (const float*)d_in[10];
  const float* c2w1 = (const float*)d_in[11];
  const float* c2b1 = (const float*)d_in[12];
  const float* c2w2 = (const float*)d_in[13];
  const float* c2b2 = (const float*)d_in[14];
  const float* mw1 = (const float*)d_in[15];
  const float* mb1 = (const float*)d_in[16];
  const float* mw2 = (const float*)d_in[17];
  const float* mb2 = (const float*)d_in[18];
  const float* mw3 = (const float*)d_in[19];
  const float* mb3 = (const float*)d_in[20];
  float* out = (float*)d_out;

  char* ws = (char*)d_ws;
  size_t off = 0;
  auto alloc = [&](size_t bytes) {
    void* p = ws + off;
    off += (bytes + 255) & ~(size_t)255;
    return p;
  };
  float* bufA = (float*)alloc((size_t)N_NODES * D * 4);
  float* bufB = (float*)alloc((size_t)N_NODES * D * 4);
  float* bufC = (float*)alloc((size_t)N_NODES * D * 4);
  int* deg = (int*)alloc((size_t)N_NODES * 4);
  int* cursor = (int*)alloc((size_t)N_NODES * 4);
  int* row_ptr = (int*)alloc((size_t)(N_NODES + 1) * 4);
  int* bsum = (int*)alloc(64 * 4);
  int* csr_src = (int*)alloc((size_t)N_EDGES * 4);
  int* csr_eid = (int*)alloc((size_t)N_EDGES * 4);
  float* hcat = (float*)alloc((size_t)N_GRAPH * 328 * 4);
  float* h1 = (float*)alloc((size_t)N_GRAPH * 512 * 4);
  float* h2 = (float*)alloc((size_t)N_GRAPH * 256 * 4);
  short* wt_hi = (short*)alloc((size_t)4 * D * D * 2);
  short* wt_lo = (short*)alloc((size_t)4 * D * D * 2);

  // weight prep (bf16 hi/lo split, transposed) + node features
  k_prep_w<<<dim3(D * D / 256, 4), 256, 0, stream>>>(c1w1, c1w2, c2w1, c2w2, wt_hi, wt_lo);
  k_atom<<<(N_NODES * 32 + 255) / 256, 256, 0, stream>>>(x_feat, atom_emb, bufA);

  // CSR build (by dst)
  int nb = (N_NODES + 1023) / 1024;
  k_zero<<<(N_NODES + 255) / 256, 256, 0, stream>>>(deg, N_NODES);
  k_count<<<(N_EDGES + 255) / 256, 256, 0, stream>>>(ei, deg);
  k_scan_blocks<<<nb, 1024, 0, stream>>>(deg, row_ptr, bsum);
  k_scan_bsums<<<1, 64, 0, stream>>>(bsum, nb, row_ptr);
  k_scan_add<<<nb, 1024, 0, stream>>>(row_ptr, cursor, bsum);
  k_fill<<<(N_EDGES + 255) / 256, 256, 0, stream>>>(ei, cursor, csr_src, csr_eid);

  int gtiles = (N_NODES + 63) / 64;
  // conv1
  k_agg<<<1536, 256, 0, stream>>>(bufA, row_ptr, csr_src, csr_eid, bondf, bond_emb, bufB);
  k_gemm_mfma<<<gtiles, 256, 0, stream>>>(bufB, wt_hi + 0 * D * D, wt_lo + 0 * D * D, c1b1, bufC, 1);
  k_gemm_mfma<<<gtiles, 256, 0, stream>>>(bufC, wt_hi + 1 * D * D, wt_lo + 1 * D * D, c1b2, bufB, 0);
  // conv2
  k_agg<<<1536, 256, 0, stream>>>(bufB, row_ptr, csr_src, csr_eid, bondf, bond_emb, bufA);
  k_gemm_mfma<<<gtiles, 256, 0, stream>>>(bufA, wt_hi + 2 * D * D, wt_lo + 2 * D * D, c2b1, bufC, 1);
  k_gemm_mfma<<<gtiles, 256, 0, stream>>>(bufC, wt_hi + 3 * D * D, wt_lo + 3 * D * D, c2b2, bufA, 0);

  // pool + head MLP
  k_pool<<<N_GRAPH / 4, 256, 0, stream>>>(bufA, batch, rdkit, hcat);
  k_mlp1<<<N_GRAPH / 8, 512, 0, stream>>>(hcat, mw1, mb1, h1);
  k_mlp2<<<N_GRAPH / 8, 256, 0, stream>>>(h1, mw2, mb2, h2);
  k_mlp3<<<N_GRAPH, 64, 0, stream>>>(h2, mw3, mb3, out);

  (void)in_sizes; (void)n_in; (void)out_size; (void)ws_size;
}

// Round 5
// 519.098 us; speedup vs baseline: 1.3174x; 1.1127x over previous
//
#include <hip/hip_runtime.h>

#define N_NODES 50000
#define N_EDGES 640000
#define N_GRAPH 1024
#define D 128
#define RD 200

typedef __attribute__((ext_vector_type(8))) short bf16x8;
typedef __attribute__((ext_vector_type(4))) float f32x4;
typedef __attribute__((ext_vector_type(4))) _Float16 half4;

static __device__ __forceinline__ unsigned short f2bf(float f) {
  unsigned u = __float_as_uint(f);
  unsigned r = (u + 0x7fff + ((u >> 16) & 1)) >> 16;
  return (unsigned short)r;
}

static __device__ __forceinline__ int lbound(const int* a, int n, int v) {
  int lo = 0, hi = n;
  while (lo < hi) { int m = (lo + hi) >> 1; if (a[m] < v) lo = m + 1; else hi = m; }
  return lo;
}

// weight prep: transpose + bf16 hi/lo split of 4 conv W mats; also zero deg
__global__ void k_prep(const float* __restrict__ w0, const float* __restrict__ w1,
                       const float* __restrict__ w2, const float* __restrict__ w3,
                       short* __restrict__ hi, short* __restrict__ lo,
                       int* __restrict__ deg) {
  const float* W = (blockIdx.y == 0) ? w0 : (blockIdx.y == 1) ? w1
                   : (blockIdx.y == 2) ? w2 : w3;
  int t = blockIdx.x * 256 + threadIdx.x;  // t = n*128 + k, t < 16384
  int n = t >> 7, k = t & 127;
  float v = W[k * D + n];
  unsigned short h = f2bf(v);
  float hf = __uint_as_float((unsigned)h << 16);
  unsigned short l = f2bf(v - hf);
  hi[blockIdx.y * (D * D) + t] = (short)h;
  lo[blockIdx.y * (D * D) + t] = (short)l;
  int lid = (blockIdx.y * 64 + blockIdx.x) * 256 + threadIdx.x;  // 0..65535
  if (lid < N_NODES) deg[lid] = 0;
}

// fused: atom encoder (fp16 out) + edge degree count
__global__ void k_atom_count(const int* __restrict__ xf, const float* __restrict__ emb,
                             _Float16* __restrict__ x16,
                             const int* __restrict__ ei, int* __restrict__ deg) {
  if (blockIdx.x < 6250) {
    int t = blockIdx.x * 256 + threadIdx.x;  // exactly 50000*32
    int node = t >> 5, c = (t & 31) << 2;
    float a0 = 0.f, a1 = 0.f, a2 = 0.f, a3 = 0.f;
#pragma unroll
    for (int f = 0; f < 9; ++f) {
      int v = xf[node * 9 + f];
      float4 e4 = *(const float4*)&emb[(f * 64 + v) * D + c];
      a0 += e4.x; a1 += e4.y; a2 += e4.z; a3 += e4.w;
    }
    half4 o;
    o.x = (_Float16)a0; o.y = (_Float16)a1; o.z = (_Float16)a2; o.w = (_Float16)a3;
    *(half4*)&x16[(size_t)node * D + c] = o;
  } else {
    int e = (blockIdx.x - 6250) * 256 + threadIdx.x;
    if (e < N_EDGES) atomicAdd(&deg[ei[N_EDGES + e]], 1);
  }
}

__global__ void k_scan_blocks(const int* __restrict__ deg, int* __restrict__ excl,
                              int* __restrict__ bsum) {
  __shared__ int sd[1024];
  int i = blockIdx.x * 1024 + threadIdx.x;
  int v = (i < N_NODES) ? deg[i] : 0;
  sd[threadIdx.x] = v;
  __syncthreads();
  for (int off = 1; off < 1024; off <<= 1) {
    int t = (threadIdx.x >= (unsigned)off) ? sd[threadIdx.x - off] : 0;
    __syncthreads();
    sd[threadIdx.x] += t;
    __syncthreads();
  }
  if (i < N_NODES) excl[i] = sd[threadIdx.x] - v;
  if (threadIdx.x == 1023) bsum[blockIdx.x] = sd[1023];
}

__global__ void k_scan_bsums(int* __restrict__ bsum, int nb, int* __restrict__ row_ptr) {
  int lane = threadIdx.x;
  int v = (lane < nb) ? bsum[lane] : 0;
  int orig = v;
#pragma unroll
  for (int off = 1; off < 64; off <<= 1) {
    int t = __shfl_up(v, off);
    if (lane >= off) v += t;
  }
  if (lane < nb) bsum[lane] = v - orig;
  if (lane == 63) row_ptr[N_NODES] = v;
}

__global__ void k_scan_add(int* __restrict__ row_ptr, int* __restrict__ cursor,
                           const int* __restrict__ bsum) {
  int i = blockIdx.x * 1024 + threadIdx.x;
  if (i < N_NODES) {
    int r = row_ptr[i] + bsum[blockIdx.x];
    row_ptr[i] = r;
    cursor[i] = r;
  }
}

// fill CSR: csr2[pos] = {src, packed bond features}
__global__ void k_fill(const int* __restrict__ ei, const int* __restrict__ bondf,
                       int* __restrict__ cursor, int2* __restrict__ csr2) {
  int e = blockIdx.x * 256 + threadIdx.x;
  if (e >= N_EDGES) return;
  int s = ei[e], d = ei[N_EDGES + e];
  int f0 = bondf[e * 3], f1 = bondf[e * 3 + 1], f2 = bondf[e * 3 + 2];
  int pos = atomicAdd(&cursor[d], 1);
  int2 v; v.x = s; v.y = f0 | (f1 << 4) | (f2 << 8);
  csr2[pos] = v;
}

// out[i] = x[i] + sum_j relu(x[src] + bond_emb_sum) ; fp16 gathers (256B rows),
// fp32 math after conversion.
__global__ __launch_bounds__(256) void k_agg(
    const _Float16* __restrict__ x16, const int* __restrict__ row_ptr,
    const int2* __restrict__ csr2, const float* __restrict__ bemb,
    float* __restrict__ out) {
  __shared__ half4 sB[1536];  // 48 rows x 128 cols fp16 = 12 KB
  for (int t = threadIdx.x; t < 1536; t += blockDim.x) {
    float4 v = *(const float4*)&bemb[t * 4];
    half4 h;
    h.x = (_Float16)v.x; h.y = (_Float16)v.y;
    h.z = (_Float16)v.z; h.w = (_Float16)v.w;
    sB[t] = h;
  }
  __syncthreads();
  int lane = threadIdx.x & 63;
  int half_ = lane >> 5;
  int l31 = lane & 31;
  int c4h = l31 * 4;  // 4 halves per lane
  int wid = blockIdx.x * (blockDim.x >> 6) + (threadIdx.x >> 6);
  int nw = gridDim.x * (blockDim.x >> 6);
  for (int i = wid; i < N_NODES; i += nw) {
    f32x4 ac[4];
#pragma unroll
    for (int u = 0; u < 4; ++u) ac[u] = (f32x4){0.f, 0.f, 0.f, 0.f};
    int e0 = row_ptr[i], e1 = row_ptr[i + 1];
    int j = e0 + half_;
#define EDGE(u, jj)                                                          \
    {                                                                        \
      int2 ed = csr2[jj];                                                    \
      half4 xr = *(const half4*)&x16[(size_t)ed.x * D + c4h];                \
      int p = ed.y;                                                          \
      f32x4 xv = __builtin_convertvector(xr, f32x4);                         \
      f32x4 b0 = __builtin_convertvector(sB[(p & 15) * 32 + l31], f32x4);    \
      f32x4 b1 = __builtin_convertvector(sB[(16 + ((p >> 4) & 15)) * 32 + l31], f32x4); \
      f32x4 b2 = __builtin_convertvector(sB[(32 + (p >> 8)) * 32 + l31], f32x4); \
      f32x4 m = xv + b0 + b1 + b2;                                           \
      m.x = fmaxf(m.x, 0.f); m.y = fmaxf(m.y, 0.f);                          \
      m.z = fmaxf(m.z, 0.f); m.w = fmaxf(m.w, 0.f);                          \
      ac[u] += m;                                                            \
    }
    for (; j + 6 < e1; j += 8) {
      EDGE(0, j) EDGE(1, j + 2) EDGE(2, j + 4) EDGE(3, j + 6)
    }
    for (; j < e1; j += 2) EDGE(0, j)
#undef EDGE
    f32x4 acc = (ac[0] + ac[1]) + (ac[2] + ac[3]);
    acc.x += __shfl_xor(acc.x, 32);
    acc.y += __shfl_xor(acc.y, 32);
    acc.z += __shfl_xor(acc.z, 32);
    acc.w += __shfl_xor(acc.w, 32);
    if (half_ == 0) {
      half4 sr = *(const half4*)&x16[(size_t)i * D + c4h];
      f32x4 sv = __builtin_convertvector(sr, f32x4);
      f32x4 o = sv + acc;
      *(f32x4*)&out[(size_t)i * D + c4h] = o;
    }
  }
}

// fused GINE nn: out = relu(A@W1+b1)@W2 + b2 ; MFMA bf16 hi/lo split,
// intermediate relayout C->A via per-wave LDS tile (stride 132).
__global__ __launch_bounds__(256) void k_conv(
    const float* __restrict__ A,
    const short* __restrict__ W1h, const short* __restrict__ W1l,
    const float* __restrict__ b1,
    const short* __restrict__ W2h, const short* __restrict__ W2l,
    const float* __restrict__ b2,
    float* __restrict__ O32, _Float16* __restrict__ O16, int out_half) {
  __shared__ float sT[4][16 * 132];  // 33 KB
  int w = threadIdx.x >> 6, lane = threadIdx.x & 63;
  int m0 = blockIdx.x * 64 + w * 16;
  int col16 = lane & 15, q = lane >> 4;
  bf16x8 ahi[4], alo[4];
#define SPLIT_ARR(dsth, dstl, kk, v)                     \
    {                                                    \
      unsigned short h_ = f2bf(v);                       \
      float hf_ = __uint_as_float((unsigned)h_ << 16);   \
      dsth[kk][_i] = (short)h_;                          \
      dstl[kk][_i] = (short)f2bf((v) - hf_);             \
    }
  {
    int row = m0 + col16;
    int rc = row < N_NODES ? row : N_NODES - 1;
    const float* Ar = A + (size_t)rc * D + q * 8;
#pragma unroll
    for (int kk = 0; kk < 4; ++kk) {
      float4 v0 = *(const float4*)(Ar + kk * 32);
      float4 v1 = *(const float4*)(Ar + kk * 32 + 4);
      float vs[8] = {v0.x, v0.y, v0.z, v0.w, v1.x, v1.y, v1.z, v1.w};
#pragma unroll
      for (int _i = 0; _i < 8; ++_i) SPLIT_ARR(ahi, alo, kk, vs[_i])
    }
  }
  // layer 1 -> LDS tile (relu + bias)
#pragma unroll
  for (int n0 = 0; n0 < 8; ++n0) {
    f32x4 acc = {0.f, 0.f, 0.f, 0.f};
    const short* wh = W1h + (n0 * 16 + col16) * D + q * 8;
    const short* wl = W1l + (n0 * 16 + col16) * D + q * 8;
#pragma unroll
    for (int kk = 0; kk < 4; ++kk) {
      bf16x8 bh = *(const bf16x8*)(wh + kk * 32);
      bf16x8 bl = *(const bf16x8*)(wl + kk * 32);
      acc = __builtin_amdgcn_mfma_f32_16x16x32_bf16(ahi[kk], bh, acc, 0, 0, 0);
      acc = __builtin_amdgcn_mfma_f32_16x16x32_bf16(ahi[kk], bl, acc, 0, 0, 0);
      acc = __builtin_amdgcn_mfma_f32_16x16x32_bf16(alo[kk], bh, acc, 0, 0, 0);
    }
    float bb = b1[n0 * 16 + col16];
#pragma unroll
    for (int r = 0; r < 4; ++r)
      sT[w][(q * 4 + r) * 132 + n0 * 16 + col16] = fmaxf(acc[r] + bb, 0.f);
  }
  __syncthreads();
  // relayout: read A2 fragments, split
  bf16x8 a2h[4], a2l[4];
  {
    const float* tr = &sT[w][col16 * 132 + q * 8];
#pragma unroll
    for (int kk = 0; kk < 4; ++kk) {
      float4 v0 = *(const float4*)(tr + kk * 32);
      float4 v1 = *(const float4*)(tr + kk * 32 + 4);
      float vs[8] = {v0.x, v0.y, v0.z, v0.w, v1.x, v1.y, v1.z, v1.w};
#pragma unroll
      for (int _i = 0; _i < 8; ++_i) SPLIT_ARR(a2h, a2l, kk, vs[_i])
    }
  }
#undef SPLIT_ARR
  // layer 2 (no relu)
#pragma unroll
  for (int n0 = 0; n0 < 8; ++n0) {
    f32x4 acc = {0.f, 0.f, 0.f, 0.f};
    const short* wh = W2h + (n0 * 16 + col16) * D + q * 8;
    const short* wl = W2l + (n0 * 16 + col16) * D + q * 8;
#pragma unroll
    for (int kk = 0; kk < 4; ++kk) {
      bf16x8 bh = *(const bf16x8*)(wh + kk * 32);
      bf16x8 bl = *(const bf16x8*)(wl + kk * 32);
      acc = __builtin_amdgcn_mfma_f32_16x16x32_bf16(a2h[kk], bh, acc, 0, 0, 0);
      acc = __builtin_amdgcn_mfma_f32_16x16x32_bf16(a2h[kk], bl, acc, 0, 0, 0);
      acc = __builtin_amdgcn_mfma_f32_16x16x32_bf16(a2l[kk], bh, acc, 0, 0, 0);
    }
    int col = n0 * 16 + col16;
    float bb = b2[col];
#pragma unroll
    for (int r = 0; r < 4; ++r) {
      int row = m0 + q * 4 + r;
      if (row < N_NODES) {
        float v = acc[r] + bb;
        if (out_half) O16[(size_t)row * D + col] = (_Float16)v;
        else O32[(size_t)row * D + col] = v;
      }
    }
  }
}

// mean-pool per graph (batch sorted) + concat rdkit -> hcat[G][328]
__global__ __launch_bounds__(256) void k_pool(
    const float* __restrict__ x, const int* __restrict__ batch,
    const float* __restrict__ rdkit, float* __restrict__ hcat) {
  int g = blockIdx.x * 4 + (threadIdx.x >> 6);
  if (g >= N_GRAPH) return;
  int lane = threadIdx.x & 63;
  int lo = lbound(batch, N_NODES, g);
  int hi = lbound(batch, N_NODES, g + 1);
  float a0 = 0.f, a1 = 0.f;
  for (int i = lo; i < hi; ++i) {
    float2 v = *(const float2*)&x[(size_t)i * D + lane * 2];
    a0 += v.x; a1 += v.y;
  }
  float inv = 1.f / fmaxf((float)(hi - lo), 1.f);
  hcat[g * 328 + lane * 2] = a0 * inv;
  hcat[g * 328 + lane * 2 + 1] = a1 * inv;
  for (int r = lane; r < RD; r += 64)
    hcat[g * 328 + D + r] = rdkit[g * RD + r];
}

// h1 = relu(hcat[1024,328] @ W[328,512] + b)
__global__ __launch_bounds__(512) void k_mlp1(
    const float* __restrict__ A, const float* __restrict__ W,
    const float* __restrict__ B, float* __restrict__ O) {
  __shared__ float sA[8 * 328];
  int gbase = blockIdx.x * 8;
  for (int t = threadIdx.x; t < 8 * 328; t += 512) sA[t] = A[gbase * 328 + t];
  __syncthreads();
  int j = threadIdx.x;
  float acc[8];
#pragma unroll
  for (int i = 0; i < 8; ++i) acc[i] = 0.f;
  for (int k = 0; k < 328; k += 4) {
    float w0 = W[(k + 0) * 512 + j];
    float w1 = W[(k + 1) * 512 + j];
    float w2 = W[(k + 2) * 512 + j];
    float w3 = W[(k + 3) * 512 + j];
#pragma unroll
    for (int i = 0; i < 8; ++i) {
      float4 a = *(const float4*)&sA[i * 328 + k];
      acc[i] += a.x * w0 + a.y * w1 + a.z * w2 + a.w * w3;
    }
  }
  float bj = B[j];
#pragma unroll
  for (int i = 0; i < 8; ++i) O[(gbase + i) * 512 + j] = fmaxf(acc[i] + bj, 0.f);
}

// fused: h2 = relu(h1@W2+b2) ; out = h2@W3 + b3
__global__ __launch_bounds__(256) void k_mlp23(
    const float* __restrict__ A, const float* __restrict__ W2,
    const float* __restrict__ B2, const float* __restrict__ W3,
    const float* __restrict__ B3, float* __restrict__ out) {
  __shared__ float sA[8 * 512];
  __shared__ float sRed[4][8];
  int gbase = blockIdx.x * 8;
  for (int t = threadIdx.x; t < 8 * 512; t += 256) sA[t] = A[gbase * 512 + t];
  __syncthreads();
  int j = threadIdx.x;
  float acc[8];
#pragma unroll
  for (int i = 0; i < 8; ++i) acc[i] = 0.f;
  for (int k = 0; k < 512; k += 4) {
    float w0 = W2[(k + 0) * 256 + j];
    float w1 = W2[(k + 1) * 256 + j];
    float w2 = W2[(k + 2) * 256 + j];
    float w3 = W2[(k + 3) * 256 + j];
#pragma unroll
    for (int i = 0; i < 8; ++i) {
      float4 a = *(const float4*)&sA[i * 512 + k];
      acc[i] += a.x * w0 + a.y * w1 + a.z * w2 + a.w * w3;
    }
  }
  float bj = B2[j];
  float w3j = W3[j];
  float p[8];
#pragma unroll
  for (int i = 0; i < 8; ++i) p[i] = fmaxf(acc[i] + bj, 0.f) * w3j;
#pragma unroll
  for (int off = 32; off > 0; off >>= 1) {
#pragma unroll
    for (int i = 0; i < 8; ++i) p[i] += __shfl_down(p[i], off);
  }
  int w = threadIdx.x >> 6;
  if ((threadIdx.x & 63) == 0) {
#pragma unroll
    for (int i = 0; i < 8; ++i) sRed[w][i] = p[i];
  }
  __syncthreads();
  if (threadIdx.x < 8) {
    float s = sRed[0][threadIdx.x] + sRed[1][threadIdx.x] +
              sRed[2][threadIdx.x] + sRed[3][threadIdx.x];
    out[gbase + threadIdx.x] = s + B3[0];
  }
}

extern "C" void kernel_launch(void* const* d_in, const int* in_sizes, int n_in,
                              void* d_out, int out_size, void* d_ws, size_t ws_size,
                              hipStream_t stream) {
  const int* x_feat = (const int*)d_in[0];
  const int* ei = (const int*)d_in[1];
  const int* bondf = (const int*)d_in[2];
  const int* batch = (const int*)d_in[3];
  const float* rdkit = (const float*)d_in[4];
  const float* atom_emb = (const float*)d_in[5];
  const float* bond_emb = (const float*)d_in[6];
  const float* c1w1 = (const float*)d_in[7];
  const float* c1b1 = (const float*)d_in[8];
  const float* c1w2 = (const float*)d_in[9];
  const float* c1b2 = (const float*)d_in[10];
  const float* c2w1 = (const float*)d_in[11];
  const float* c2b1 = (const float*)d_in[12];
  const float* c2w2 = (const float*)d_in[13];
  const float* c2b2 = (const float*)d_in[14];
  const float* mw1 = (const float*)d_in[15];
  const float* mb1 = (const float*)d_in[16];
  const float* mw2 = (const float*)d_in[17];
  const float* mb2 = (const float*)d_in[18];
  const float* mw3 = (const float*)d_in[19];
  const float* mb3 = (const float*)d_in[20];
  float* out = (float*)d_out;

  char* ws = (char*)d_ws;
  size_t off = 0;
  auto alloc = [&](size_t bytes) {
    void* p = ws + off;
    off += (bytes + 255) & ~(size_t)255;
    return p;
  };
  _Float16* x16a = (_Float16*)alloc((size_t)N_NODES * D * 2);
  _Float16* x16b = (_Float16*)alloc((size_t)N_NODES * D * 2);
  float* h32 = (float*)alloc((size_t)N_NODES * D * 4);
  float* x2 = (float*)alloc((size_t)N_NODES * D * 4);
  int* deg = (int*)alloc((size_t)N_NODES * 4);
  int* cursor = (int*)alloc((size_t)N_NODES * 4);
  int* row_ptr = (int*)alloc((size_t)(N_NODES + 1) * 4);
  int* bsum = (int*)alloc(64 * 4);
  int2* csr2 = (int2*)alloc((size_t)N_EDGES * 8);
  float* hcat = (float*)alloc((size_t)N_GRAPH * 328 * 4);
  float* h1buf = (float*)alloc((size_t)N_GRAPH * 512 * 4);
  short* wt_hi = (short*)alloc((size_t)4 * D * D * 2);
  short* wt_lo = (short*)alloc((size_t)4 * D * D * 2);

  // prep (W split + deg zero), then atom-encode + degree count
  k_prep<<<dim3(64, 4), 256, 0, stream>>>(c1w1, c1w2, c2w1, c2w2, wt_hi, wt_lo, deg);
  k_atom_count<<<6250 + 2500, 256, 0, stream>>>(x_feat, atom_emb, x16a, ei, deg);

  // CSR scan + fill
  int nb = (N_NODES + 1023) / 1024;
  k_scan_blocks<<<nb, 1024, 0, stream>>>(deg, row_ptr, bsum);
  k_scan_bsums<<<1, 64, 0, stream>>>(bsum, nb, row_ptr);
  k_scan_add<<<nb, 1024, 0, stream>>>(row_ptr, cursor, bsum);
  k_fill<<<(N_EDGES + 255) / 256, 256, 0, stream>>>(ei, bondf, cursor, csr2);

  int gtiles = (N_NODES + 63) / 64;
  // conv1: agg -> fused nn -> fp16
  k_agg<<<2048, 256, 0, stream>>>(x16a, row_ptr, csr2, bond_emb, h32);
  k_conv<<<gtiles, 256, 0, stream>>>(h32, wt_hi + 0 * D * D, wt_lo + 0 * D * D, c1b1,
                                     wt_hi + 1 * D * D, wt_lo + 1 * D * D, c1b2,
                                     nullptr, x16b, 1);
  // conv2: agg -> fused nn -> fp32
  k_agg<<<2048, 256, 0, stream>>>(x16b, row_ptr, csr2, bond_emb, h32);
  k_conv<<<gtiles, 256, 0, stream>>>(h32, wt_hi + 2 * D * D, wt_lo + 2 * D * D, c2b1,
                                     wt_hi + 3 * D * D, wt_lo + 3 * D * D, c2b2,
                                     x2, nullptr, 0);

  // pool + head MLP
  k_pool<<<N_GRAPH / 4, 256, 0, stream>>>(x2, batch, rdkit, hcat);
  k_mlp1<<<N_GRAPH / 8, 512, 0, stream>>>(hcat, mw1, mb1, h1buf);
  k_mlp23<<<N_GRAPH / 8, 256, 0, stream>>>(h1buf, mw2, mb2, mw3, mb3, out);

  (void)in_sizes; (void)n_in; (void)out_size; (void)ws_size;
}

// Round 6
// 505.756 us; speedup vs baseline: 1.3521x; 1.0264x over previous
//
#include <hip/hip_runtime.h>

#define N_NODES 50000
#define N_EDGES 640000
#define N_GRAPH 1024
#define D 128
#define RD 200

typedef __attribute__((ext_vector_type(8))) short bf16x8;
typedef __attribute__((ext_vector_type(4))) float f32x4;
typedef __attribute__((ext_vector_type(8))) float f32x8;
typedef __attribute__((ext_vector_type(4))) _Float16 half4;
typedef __attribute__((ext_vector_type(8))) _Float16 half8;

static __device__ __forceinline__ unsigned short f2bf(float f) {
  unsigned u = __float_as_uint(f);
  unsigned r = (u + 0x7fff + ((u >> 16) & 1)) >> 16;
  return (unsigned short)r;
}

static __device__ __forceinline__ int lbound(const int* a, int n, int v) {
  int lo = 0, hi = n;
  while (lo < hi) { int m = (lo + hi) >> 1; if (a[m] < v) lo = m + 1; else hi = m; }
  return lo;
}

// weight prep: transpose + bf16 hi/lo split of 4 conv W mats; also zero deg
__global__ void k_prep(const float* __restrict__ w0, const float* __restrict__ w1,
                       const float* __restrict__ w2, const float* __restrict__ w3,
                       short* __restrict__ hi, short* __restrict__ lo,
                       int* __restrict__ deg) {
  const float* W = (blockIdx.y == 0) ? w0 : (blockIdx.y == 1) ? w1
                   : (blockIdx.y == 2) ? w2 : w3;
  int t = blockIdx.x * 256 + threadIdx.x;  // t = n*128 + k, t < 16384
  int n = t >> 7, k = t & 127;
  float v = W[k * D + n];
  unsigned short h = f2bf(v);
  float hf = __uint_as_float((unsigned)h << 16);
  unsigned short l = f2bf(v - hf);
  hi[blockIdx.y * (D * D) + t] = (short)h;
  lo[blockIdx.y * (D * D) + t] = (short)l;
  int lid = (blockIdx.y * 64 + blockIdx.x) * 256 + threadIdx.x;  // 0..65535
  if (lid < N_NODES) deg[lid] = 0;
}

// fused: atom encoder (fp16 out) + edge degree count
__global__ void k_atom_count(const int* __restrict__ xf, const float* __restrict__ emb,
                             _Float16* __restrict__ x16,
                             const int* __restrict__ ei, int* __restrict__ deg) {
  if (blockIdx.x < 6250) {
    int t = blockIdx.x * 256 + threadIdx.x;  // exactly 50000*32
    int node = t >> 5, c = (t & 31) << 2;
    float a0 = 0.f, a1 = 0.f, a2 = 0.f, a3 = 0.f;
#pragma unroll
    for (int f = 0; f < 9; ++f) {
      int v = xf[node * 9 + f];
      float4 e4 = *(const float4*)&emb[(f * 64 + v) * D + c];
      a0 += e4.x; a1 += e4.y; a2 += e4.z; a3 += e4.w;
    }
    half4 o;
    o.x = (_Float16)a0; o.y = (_Float16)a1; o.z = (_Float16)a2; o.w = (_Float16)a3;
    *(half4*)&x16[(size_t)node * D + c] = o;
  } else {
    int e = (blockIdx.x - 6250) * 256 + threadIdx.x;
    if (e < N_EDGES) atomicAdd(&deg[ei[N_EDGES + e]], 1);
  }
}

__global__ void k_scan_blocks(const int* __restrict__ deg, int* __restrict__ excl,
                              int* __restrict__ bsum) {
  __shared__ int sd[1024];
  int i = blockIdx.x * 1024 + threadIdx.x;
  int v = (i < N_NODES) ? deg[i] : 0;
  sd[threadIdx.x] = v;
  __syncthreads();
  for (int off = 1; off < 1024; off <<= 1) {
    int t = (threadIdx.x >= (unsigned)off) ? sd[threadIdx.x - off] : 0;
    __syncthreads();
    sd[threadIdx.x] += t;
    __syncthreads();
  }
  if (i < N_NODES) excl[i] = sd[threadIdx.x] - v;
  if (threadIdx.x == 1023) bsum[blockIdx.x] = sd[1023];
}

__global__ void k_scan_bsums(int* __restrict__ bsum, int nb, int* __restrict__ row_ptr) {
  int lane = threadIdx.x;
  int v = (lane < nb) ? bsum[lane] : 0;
  int orig = v;
#pragma unroll
  for (int off = 1; off < 64; off <<= 1) {
    int t = __shfl_up(v, off);
    if (lane >= off) v += t;
  }
  if (lane < nb) bsum[lane] = v - orig;
  if (lane == 63) row_ptr[N_NODES] = v;
}

__global__ void k_scan_add(int* __restrict__ row_ptr, int* __restrict__ cursor,
                           const int* __restrict__ bsum) {
  int i = blockIdx.x * 1024 + threadIdx.x;
  if (i < N_NODES) {
    int r = row_ptr[i] + bsum[blockIdx.x];
    row_ptr[i] = r;
    cursor[i] = r;
  }
}

// fill CSR: csr2[pos] = {src, packed bond features}
__global__ void k_fill(const int* __restrict__ ei, const int* __restrict__ bondf,
                       int* __restrict__ cursor, int2* __restrict__ csr2) {
  int e = blockIdx.x * 256 + threadIdx.x;
  if (e >= N_EDGES) return;
  int s = ei[e], d = ei[N_EDGES + e];
  int f0 = bondf[e * 3], f1 = bondf[e * 3 + 1], f2 = bondf[e * 3 + 2];
  int pos = atomicAdd(&cursor[d], 1);
  int2 v; v.x = s; v.y = f0 | (f1 << 4) | (f2 << 8);
  csr2[pos] = v;
}

// out[i] = x[i] + sum_j relu(x[src] + bond_emb_sum)
// quarter-wave per edge: 16 lanes x 16B fp16 gathers, fp32 math.
__global__ __launch_bounds__(256) void k_agg(
    const _Float16* __restrict__ x16, const int* __restrict__ row_ptr,
    const int2* __restrict__ csr2, const float* __restrict__ bemb,
    float* __restrict__ out) {
  __shared__ half8 sB[48 * 16];  // 12 KB fp16 bond table
  for (int t = threadIdx.x; t < 768; t += blockDim.x) {
    float4 v0 = *(const float4*)&bemb[t * 8];
    float4 v1 = *(const float4*)&bemb[t * 8 + 4];
    half8 h;
    h[0] = (_Float16)v0.x; h[1] = (_Float16)v0.y; h[2] = (_Float16)v0.z; h[3] = (_Float16)v0.w;
    h[4] = (_Float16)v1.x; h[5] = (_Float16)v1.y; h[6] = (_Float16)v1.z; h[7] = (_Float16)v1.w;
    sB[t] = h;
  }
  __syncthreads();
  int lane = threadIdx.x & 63;
  int quad = lane >> 4;
  int l15 = lane & 15;
  int c8 = l15 * 8;  // 8 halves = 16B
  int wid = blockIdx.x * (blockDim.x >> 6) + (threadIdx.x >> 6);
  int nw = gridDim.x * (blockDim.x >> 6);
  for (int i = wid; i < N_NODES; i += nw) {
    f32x8 ac[2];
    ac[0] = (f32x8)(0.f); ac[1] = (f32x8)(0.f);
    int e0 = row_ptr[i], e1 = row_ptr[i + 1];
    int j = e0 + quad;
#define EDGE(u, jj)                                                          \
    {                                                                        \
      int2 ed = csr2[jj];                                                    \
      half8 xr = *(const half8*)&x16[(size_t)ed.x * D + c8];                 \
      int p = ed.y;                                                          \
      half8 b0 = sB[(p & 15) * 16 + l15];                                    \
      half8 b1 = sB[256 + ((p >> 4) & 15) * 16 + l15];                       \
      half8 b2 = sB[512 + (p >> 8) * 16 + l15];                              \
      f32x8 m = __builtin_convertvector(xr, f32x8) +                         \
                __builtin_convertvector(b0, f32x8) +                         \
                __builtin_convertvector(b1, f32x8) +                         \
                __builtin_convertvector(b2, f32x8);                          \
      _Pragma("unroll")                                                      \
      for (int tt = 0; tt < 8; ++tt) m[tt] = fmaxf(m[tt], 0.f);              \
      ac[u] += m;                                                            \
    }
    for (; j + 4 < e1; j += 8) { EDGE(0, j) EDGE(1, j + 4) }
    for (; j < e1; j += 4) EDGE(0, j)
#undef EDGE
    f32x8 acc = ac[0] + ac[1];
#pragma unroll
    for (int tt = 0; tt < 8; ++tt) {
      acc[tt] += __shfl_xor(acc[tt], 16);
      acc[tt] += __shfl_xor(acc[tt], 32);
    }
    if (quad == 0) {
      half8 sr = *(const half8*)&x16[(size_t)i * D + c8];
      f32x8 o = __builtin_convertvector(sr, f32x8) + acc;
      *(f32x8*)&out[(size_t)i * D + c8] = o;
    }
  }
}

// fused GINE nn: out = relu(A@W1+b1)@W2 + b2 ; MFMA bf16 hi/lo split.
// One wave per block, 16-row tile (grid = 50000/16 = 3125 exactly).
// Double-buffered W fragments + 3 independent acc chains.
__global__ __launch_bounds__(64) void k_conv(
    const float* __restrict__ A,
    const short* __restrict__ W1h, const short* __restrict__ W1l,
    const float* __restrict__ b1,
    const short* __restrict__ W2h, const short* __restrict__ W2l,
    const float* __restrict__ b2,
    float* __restrict__ O32, _Float16* __restrict__ O16, int out_half) {
  __shared__ float sT[16 * 132];  // 8.4 KB per-wave tile
  int lane = threadIdx.x;
  int m0 = blockIdx.x * 16;
  int col16 = lane & 15, q = lane >> 4;
  bf16x8 ahi[4], alo[4];
#define SPLIT_ARR(dsth, dstl, kk, v)                     \
    {                                                    \
      unsigned short h_ = f2bf(v);                       \
      float hf_ = __uint_as_float((unsigned)h_ << 16);   \
      dsth[kk][_i] = (short)h_;                          \
      dstl[kk][_i] = (short)f2bf((v) - hf_);             \
    }
  {
    const float* Ar = A + (size_t)(m0 + col16) * D + q * 8;
#pragma unroll
    for (int kk = 0; kk < 4; ++kk) {
      float4 v0 = *(const float4*)(Ar + kk * 32);
      float4 v1 = *(const float4*)(Ar + kk * 32 + 4);
      float vs[8] = {v0.x, v0.y, v0.z, v0.w, v1.x, v1.y, v1.z, v1.w};
#pragma unroll
      for (int _i = 0; _i < 8; ++_i) SPLIT_ARR(ahi, alo, kk, vs[_i])
    }
  }
  // ---- layer 1: relu(A@W1+b1) -> sT ----
  {
    const short* wh0 = W1h + col16 * D + q * 8;
    const short* wl0 = W1l + col16 * D + q * 8;
    bf16x8 pbh[4], pbl[4];
#pragma unroll
    for (int kk = 0; kk < 4; ++kk) {
      pbh[kk] = *(const bf16x8*)(wh0 + kk * 32);
      pbl[kk] = *(const bf16x8*)(wl0 + kk * 32);
    }
#pragma unroll
    for (int n0 = 0; n0 < 8; ++n0) {
      bf16x8 cbh[4], cbl[4];
#pragma unroll
      for (int kk = 0; kk < 4; ++kk) { cbh[kk] = pbh[kk]; cbl[kk] = pbl[kk]; }
      if (n0 < 7) {
        const short* whn = wh0 + (n0 + 1) * 16 * D;
        const short* wln = wl0 + (n0 + 1) * 16 * D;
#pragma unroll
        for (int kk = 0; kk < 4; ++kk) {
          pbh[kk] = *(const bf16x8*)(whn + kk * 32);
          pbl[kk] = *(const bf16x8*)(wln + kk * 32);
        }
      }
      f32x4 a0 = {0.f, 0.f, 0.f, 0.f}, a1 = {0.f, 0.f, 0.f, 0.f}, a2 = {0.f, 0.f, 0.f, 0.f};
#pragma unroll
      for (int kk = 0; kk < 4; ++kk) {
        a0 = __builtin_amdgcn_mfma_f32_16x16x32_bf16(ahi[kk], cbh[kk], a0, 0, 0, 0);
        a1 = __builtin_amdgcn_mfma_f32_16x16x32_bf16(ahi[kk], cbl[kk], a1, 0, 0, 0);
        a2 = __builtin_amdgcn_mfma_f32_16x16x32_bf16(alo[kk], cbh[kk], a2, 0, 0, 0);
      }
      float bb = b1[n0 * 16 + col16];
#pragma unroll
      for (int r = 0; r < 4; ++r)
        sT[(q * 4 + r) * 132 + n0 * 16 + col16] = fmaxf(a0[r] + a1[r] + a2[r] + bb, 0.f);
    }
  }
  __syncthreads();
  // relayout C->A + split
  bf16x8 a2h[4], a2l[4];
  {
    const float* tr = &sT[col16 * 132 + q * 8];
#pragma unroll
    for (int kk = 0; kk < 4; ++kk) {
      float4 v0 = *(const float4*)(tr + kk * 32);
      float4 v1 = *(const float4*)(tr + kk * 32 + 4);
      float vs[8] = {v0.x, v0.y, v0.z, v0.w, v1.x, v1.y, v1.z, v1.w};
#pragma unroll
      for (int _i = 0; _i < 8; ++_i) SPLIT_ARR(a2h, a2l, kk, vs[_i])
    }
  }
#undef SPLIT_ARR
  // ---- layer 2 (no relu) ----
  {
    const short* wh0 = W2h + col16 * D + q * 8;
    const short* wl0 = W2l + col16 * D + q * 8;
    bf16x8 pbh[4], pbl[4];
#pragma unroll
    for (int kk = 0; kk < 4; ++kk) {
      pbh[kk] = *(const bf16x8*)(wh0 + kk * 32);
      pbl[kk] = *(const bf16x8*)(wl0 + kk * 32);
    }
#pragma unroll
    for (int n0 = 0; n0 < 8; ++n0) {
      bf16x8 cbh[4], cbl[4];
#pragma unroll
      for (int kk = 0; kk < 4; ++kk) { cbh[kk] = pbh[kk]; cbl[kk] = pbl[kk]; }
      if (n0 < 7) {
        const short* whn = wh0 + (n0 + 1) * 16 * D;
        const short* wln = wl0 + (n0 + 1) * 16 * D;
#pragma unroll
        for (int kk = 0; kk < 4; ++kk) {
          pbh[kk] = *(const bf16x8*)(whn + kk * 32);
          pbl[kk] = *(const bf16x8*)(wln + kk * 32);
        }
      }
      f32x4 a0 = {0.f, 0.f, 0.f, 0.f}, a1 = {0.f, 0.f, 0.f, 0.f}, a2 = {0.f, 0.f, 0.f, 0.f};
#pragma unroll
      for (int kk = 0; kk < 4; ++kk) {
        a0 = __builtin_amdgcn_mfma_f32_16x16x32_bf16(a2h[kk], cbh[kk], a0, 0, 0, 0);
        a1 = __builtin_amdgcn_mfma_f32_16x16x32_bf16(a2h[kk], cbl[kk], a1, 0, 0, 0);
        a2 = __builtin_amdgcn_mfma_f32_16x16x32_bf16(a2l[kk], cbh[kk], a2, 0, 0, 0);
      }
      int col = n0 * 16 + col16;
      float bb = b2[col];
#pragma unroll
      for (int r = 0; r < 4; ++r) {
        int row = m0 + q * 4 + r;
        float v = a0[r] + a1[r] + a2[r] + bb;
        if (out_half) O16[(size_t)row * D + col] = (_Float16)v;
        else O32[(size_t)row * D + col] = v;
      }
    }
  }
}

// mean-pool per graph (batch sorted) + concat rdkit -> hcat[G][328]
__global__ __launch_bounds__(256) void k_pool(
    const float* __restrict__ x, const int* __restrict__ batch,
    const float* __restrict__ rdkit, float* __restrict__ hcat) {
  int g = blockIdx.x * 4 + (threadIdx.x >> 6);
  if (g >= N_GRAPH) return;
  int lane = threadIdx.x & 63;
  int lo = lbound(batch, N_NODES, g);
  int hi = lbound(batch, N_NODES, g + 1);
  float a0 = 0.f, a1 = 0.f;
  for (int i = lo; i < hi; ++i) {
    float2 v = *(const float2*)&x[(size_t)i * D + lane * 2];
    a0 += v.x; a1 += v.y;
  }
  float inv = 1.f / fmaxf((float)(hi - lo), 1.f);
  hcat[g * 328 + lane * 2] = a0 * inv;
  hcat[g * 328 + lane * 2 + 1] = a1 * inv;
  for (int r = lane; r < RD; r += 64)
    hcat[g * 328 + D + r] = rdkit[g * RD + r];
}

// h1 = relu(hcat[1024,328] @ W[328,512] + b) ; 16 graphs/block
__global__ __launch_bounds__(512) void k_mlp1(
    const float* __restrict__ A, const float* __restrict__ W,
    const float* __restrict__ B, float* __restrict__ O) {
  __shared__ float sA[16 * 328];
  int gbase = blockIdx.x * 16;
  for (int t = threadIdx.x; t < 16 * 328; t += 512) sA[t] = A[gbase * 328 + t];
  __syncthreads();
  int j = threadIdx.x;
  float acc[16];
#pragma unroll
  for (int i = 0; i < 16; ++i) acc[i] = 0.f;
  for (int k = 0; k < 328; k += 4) {
    float w0 = W[(k + 0) * 512 + j];
    float w1 = W[(k + 1) * 512 + j];
    float w2 = W[(k + 2) * 512 + j];
    float w3 = W[(k + 3) * 512 + j];
#pragma unroll
    for (int i = 0; i < 16; ++i) {
      float4 a = *(const float4*)&sA[i * 328 + k];
      acc[i] += a.x * w0 + a.y * w1 + a.z * w2 + a.w * w3;
    }
  }
  float bj = B[j];
#pragma unroll
  for (int i = 0; i < 16; ++i) O[(gbase + i) * 512 + j] = fmaxf(acc[i] + bj, 0.f);
}

// fused: h2 = relu(h1@W2+b2) ; out = h2@W3 + b3 ; 16 graphs/block
__global__ __launch_bounds__(256) void k_mlp23(
    const float* __restrict__ A, const float* __restrict__ W2,
    const float* __restrict__ B2, const float* __restrict__ W3,
    const float* __restrict__ B3, float* __restrict__ out) {
  __shared__ float sA[16 * 512];
  __shared__ float sRed[4][16];
  int gbase = blockIdx.x * 16;
  for (int t = threadIdx.x; t < 16 * 512; t += 256) sA[t] = A[gbase * 512 + t];
  __syncthreads();
  int j = threadIdx.x;
  float acc[16];
#pragma unroll
  for (int i = 0; i < 16; ++i) acc[i] = 0.f;
  for (int k = 0; k < 512; k += 4) {
    float w0 = W2[(k + 0) * 256 + j];
    float w1 = W2[(k + 1) * 256 + j];
    float w2 = W2[(k + 2) * 256 + j];
    float w3 = W2[(k + 3) * 256 + j];
#pragma unroll
    for (int i = 0; i < 16; ++i) {
      float4 a = *(const float4*)&sA[i * 512 + k];
      acc[i] += a.x * w0 + a.y * w1 + a.z * w2 + a.w * w3;
    }
  }
  float bj = B2[j];
  float w3j = W3[j];
  float p[16];
#pragma unroll
  for (int i = 0; i < 16; ++i) p[i] = fmaxf(acc[i] + bj, 0.f) * w3j;
#pragma unroll
  for (int off = 32; off > 0; off >>= 1) {
#pragma unroll
    for (int i = 0; i < 16; ++i) p[i] += __shfl_down(p[i], off);
  }
  int w = threadIdx.x >> 6;
  if ((threadIdx.x & 63) == 0) {
#pragma unroll
    for (int i = 0; i < 16; ++i) sRed[w][i] = p[i];
  }
  __syncthreads();
  if (threadIdx.x < 16) {
    float s = sRed[0][threadIdx.x] + sRed[1][threadIdx.x] +
              sRed[2][threadIdx.x] + sRed[3][threadIdx.x];
    out[gbase + threadIdx.x] = s + B3[0];
  }
}

extern "C" void kernel_launch(void* const* d_in, const int* in_sizes, int n_in,
                              void* d_out, int out_size, void* d_ws, size_t ws_size,
                              hipStream_t stream) {
  const int* x_feat = (const int*)d_in[0];
  const int* ei = (const int*)d_in[1];
  const int* bondf = (const int*)d_in[2];
  const int* batch = (const int*)d_in[3];
  const float* rdkit = (const float*)d_in[4];
  const float* atom_emb = (const float*)d_in[5];
  const float* bond_emb = (const float*)d_in[6];
  const float* c1w1 = (const float*)d_in[7];
  const float* c1b1 = (const float*)d_in[8];
  const float* c1w2 = (const float*)d_in[9];
  const float* c1b2 = (const float*)d_in[10];
  const float* c2w1 = (const float*)d_in[11];
  const float* c2b1 = (const float*)d_in[12];
  const float* c2w2 = (const float*)d_in[13];
  const float* c2b2 = (const float*)d_in[14];
  const float* mw1 = (const float*)d_in[15];
  const float* mb1 = (const float*)d_in[16];
  const float* mw2 = (const float*)d_in[17];
  const float* mb2 = (const float*)d_in[18];
  const float* mw3 = (const float*)d_in[19];
  const float* mb3 = (const float*)d_in[20];
  float* out = (float*)d_out;

  char* ws = (char*)d_ws;
  size_t off = 0;
  auto alloc = [&](size_t bytes) {
    void* p = ws + off;
    off += (bytes + 255) & ~(size_t)255;
    return p;
  };
  _Float16* x16a = (_Float16*)alloc((size_t)N_NODES * D * 2);
  _Float16* x16b = (_Float16*)alloc((size_t)N_NODES * D * 2);
  float* h32 = (float*)alloc((size_t)N_NODES * D * 4);
  float* x2 = (float*)alloc((size_t)N_NODES * D * 4);
  int* deg = (int*)alloc((size_t)N_NODES * 4);
  int* cursor = (int*)alloc((size_t)N_NODES * 4);
  int* row_ptr = (int*)alloc((size_t)(N_NODES + 1) * 4);
  int* bsum = (int*)alloc(64 * 4);
  int2* csr2 = (int2*)alloc((size_t)N_EDGES * 8);
  float* hcat = (float*)alloc((size_t)N_GRAPH * 328 * 4);
  float* h1buf = (float*)alloc((size_t)N_GRAPH * 512 * 4);
  short* wt_hi = (short*)alloc((size_t)4 * D * D * 2);
  short* wt_lo = (short*)alloc((size_t)4 * D * D * 2);

  // prep (W split + deg zero), then atom-encode + degree count
  k_prep<<<dim3(64, 4), 256, 0, stream>>>(c1w1, c1w2, c2w1, c2w2, wt_hi, wt_lo, deg);
  k_atom_count<<<6250 + 2500, 256, 0, stream>>>(x_feat, atom_emb, x16a, ei, deg);

  // CSR scan + fill
  int nb = (N_NODES + 1023) / 1024;
  k_scan_blocks<<<nb, 1024, 0, stream>>>(deg, row_ptr, bsum);
  k_scan_bsums<<<1, 64, 0, stream>>>(bsum, nb, row_ptr);
  k_scan_add<<<nb, 1024, 0, stream>>>(row_ptr, cursor, bsum);
  k_fill<<<(N_EDGES + 255) / 256, 256, 0, stream>>>(ei, bondf, cursor, csr2);

  int gtiles16 = N_NODES / 16;  // 3125, exact
  // conv1: agg -> fused nn -> fp16
  k_agg<<<2048, 256, 0, stream>>>(x16a, row_ptr, csr2, bond_emb, h32);
  k_conv<<<gtiles16, 64, 0, stream>>>(h32, wt_hi + 0 * D * D, wt_lo + 0 * D * D, c1b1,
                                      wt_hi + 1 * D * D, wt_lo + 1 * D * D, c1b2,
                                      nullptr, x16b, 1);
  // conv2: agg -> fused nn -> fp32
  k_agg<<<2048, 256, 0, stream>>>(x16b, row_ptr, csr2, bond_emb, h32);
  k_conv<<<gtiles16, 64, 0, stream>>>(h32, wt_hi + 2 * D * D, wt_lo + 2 * D * D, c2b1,
                                      wt_hi + 3 * D * D, wt_lo + 3 * D * D, c2b2,
                                      x2, nullptr, 0);

  // pool + head MLP
  k_pool<<<N_GRAPH / 4, 256, 0, stream>>>(x2, batch, rdkit, hcat);
  k_mlp1<<<N_GRAPH / 16, 512, 0, stream>>>(hcat, mw1, mb1, h1buf);
  k_mlp23<<<N_GRAPH / 16, 256, 0, stream>>>(h1buf, mw2, mb2, mw3, mb3, out);

  (void)in_sizes; (void)n_in; (void)out_size; (void)ws_size;
}

// Round 7
// 354.633 us; speedup vs baseline: 1.9283x; 1.4261x over previous
//
#include <hip/hip_runtime.h>

#define N_NODES 50000
#define N_EDGES 640000
#define N_GRAPH 1024
#define D 128
#define RD 200

typedef __attribute__((ext_vector_type(4))) float f32x4;
typedef __attribute__((ext_vector_type(8))) float f32x8;
typedef __attribute__((ext_vector_type(4))) _Float16 half4;
typedef __attribute__((ext_vector_type(8))) _Float16 half8;

static __device__ __forceinline__ int lbound(const int* a, int n, int v) {
  int lo = 0, hi = n;
  while (lo < hi) { int m = (lo + hi) >> 1; if (a[m] < v) lo = m + 1; else hi = m; }
  return lo;
}

// ---- prep: all weights -> fp16 MFMA-fragment-linear order; zero deg ----
// conv frags (4 mats, 32 frags each), W1t head (352 frags), W2t head (256 frags)
__global__ void k_prep(const float* __restrict__ w0, const float* __restrict__ w1,
                       const float* __restrict__ w2, const float* __restrict__ w3,
                       const float* __restrict__ mw1, const float* __restrict__ mw2,
                       _Float16* __restrict__ cWf,   // [4][32*64*8]
                       _Float16* __restrict__ W1f,   // [352*64*8]
                       _Float16* __restrict__ W2f,   // [256*64*8]
                       int* __restrict__ deg) {
  int t = blockIdx.x * 256 + threadIdx.x;  // 0..65535
  if (t < N_NODES) deg[t] = 0;
  if (t < 8192) {
    // conv: mat = t>>11, r = t&2047; frag = r>>6 (n0*4+kk), lane = r&63
    int mat = t >> 11, r = t & 2047;
    int frag = r >> 6, lane = r & 63;
    int n0 = frag >> 2, kk = frag & 3;
    int n = n0 * 16 + (lane & 15);
    int kb = (lane >> 4) * 8 + kk * 32;
    const float* W = (mat == 0) ? w0 : (mat == 1) ? w1 : (mat == 2) ? w2 : w3;
    half8 o;
#pragma unroll
    for (int j = 0; j < 8; ++j) o[j] = (_Float16)W[(kb + j) * D + n];
    *(half8*)&cWf[((size_t)mat * 2048 + r) * 8] = o;
  } else if (t < 8192 + 22528) {
    int u = t - 8192;
    int frag = u >> 6, lane = u & 63;
    int n0 = frag / 11, kk = frag % 11;
    int n = n0 * 16 + (lane & 15);
    int kb = (lane >> 4) * 8 + kk * 32;
    half8 o;
#pragma unroll
    for (int j = 0; j < 8; ++j) {
      int k = kb + j;
      o[j] = (k < 328) ? (_Float16)mw1[k * 512 + n] : (_Float16)0.f;
    }
    *(half8*)&W1f[(size_t)u * 8] = o;
  } else if (t < 8192 + 22528 + 16384) {
    int u = t - 8192 - 22528;
    int frag = u >> 6, lane = u & 63;
    int n0 = frag >> 4, kk = frag & 15;
    int n = n0 * 16 + (lane & 15);
    int kb = (lane >> 4) * 8 + kk * 32;
    half8 o;
#pragma unroll
    for (int j = 0; j < 8; ++j) o[j] = (_Float16)mw2[(kb + j) * 256 + n];
    *(half8*)&W2f[(size_t)u * 8] = o;
  }
}

// fused: atom encoder (fp16 out) + edge degree count
__global__ void k_atom_count(const int* __restrict__ xf, const float* __restrict__ emb,
                             _Float16* __restrict__ x16,
                             const int* __restrict__ ei, int* __restrict__ deg) {
  if (blockIdx.x < 6250) {
    int t = blockIdx.x * 256 + threadIdx.x;  // exactly 50000*32
    int node = t >> 5, c = (t & 31) << 2;
    float a0 = 0.f, a1 = 0.f, a2 = 0.f, a3 = 0.f;
#pragma unroll
    for (int f = 0; f < 9; ++f) {
      int v = xf[node * 9 + f];
      float4 e4 = *(const float4*)&emb[(f * 64 + v) * D + c];
      a0 += e4.x; a1 += e4.y; a2 += e4.z; a3 += e4.w;
    }
    half4 o;
    o.x = (_Float16)a0; o.y = (_Float16)a1; o.z = (_Float16)a2; o.w = (_Float16)a3;
    *(half4*)&x16[(size_t)node * D + c] = o;
  } else {
    int e = (blockIdx.x - 6250) * 256 + threadIdx.x;
    if (e < N_EDGES) atomicAdd(&deg[ei[N_EDGES + e]], 1);
  }
}

__global__ void k_scan_blocks(const int* __restrict__ deg, int* __restrict__ excl,
                              int* __restrict__ bsum) {
  __shared__ int sd[1024];
  int i = blockIdx.x * 1024 + threadIdx.x;
  int v = (i < N_NODES) ? deg[i] : 0;
  sd[threadIdx.x] = v;
  __syncthreads();
  for (int off = 1; off < 1024; off <<= 1) {
    int t = (threadIdx.x >= (unsigned)off) ? sd[threadIdx.x - off] : 0;
    __syncthreads();
    sd[threadIdx.x] += t;
    __syncthreads();
  }
  if (i < N_NODES) excl[i] = sd[threadIdx.x] - v;
  if (threadIdx.x == 1023) bsum[blockIdx.x] = sd[1023];
}

__global__ void k_scan_bsums(int* __restrict__ bsum, int nb, int* __restrict__ row_ptr) {
  int lane = threadIdx.x;
  int v = (lane < nb) ? bsum[lane] : 0;
  int orig = v;
#pragma unroll
  for (int off = 1; off < 64; off <<= 1) {
    int t = __shfl_up(v, off);
    if (lane >= off) v += t;
  }
  if (lane < nb) bsum[lane] = v - orig;
  if (lane == 63) row_ptr[N_NODES] = v;
}

__global__ void k_scan_add(int* __restrict__ row_ptr, int* __restrict__ cursor,
                           const int* __restrict__ bsum) {
  int i = blockIdx.x * 1024 + threadIdx.x;
  if (i < N_NODES) {
    int r = row_ptr[i] + bsum[blockIdx.x];
    row_ptr[i] = r;
    cursor[i] = r;
  }
}

__global__ void k_fill(const int* __restrict__ ei, const int* __restrict__ bondf,
                       int* __restrict__ cursor, int2* __restrict__ csr2) {
  int e = blockIdx.x * 256 + threadIdx.x;
  if (e >= N_EDGES) return;
  int s = ei[e], d = ei[N_EDGES + e];
  int f0 = bondf[e * 3], f1 = bondf[e * 3 + 1], f2 = bondf[e * 3 + 2];
  int pos = atomicAdd(&cursor[d], 1);
  int2 v; v.x = s; v.y = f0 | (f1 << 4) | (f2 << 8);
  csr2[pos] = v;
}

// out[i] = x[i] + sum_j relu(x[src] + bond_emb_sum) ; fp16 in, fp16 out
__global__ __launch_bounds__(256) void k_agg(
    const _Float16* __restrict__ x16, const int* __restrict__ row_ptr,
    const int2* __restrict__ csr2, const float* __restrict__ bemb,
    _Float16* __restrict__ out) {
  __shared__ half8 sB[48 * 16];  // 12 KB fp16 bond table
  for (int t = threadIdx.x; t < 768; t += blockDim.x) {
    float4 v0 = *(const float4*)&bemb[t * 8];
    float4 v1 = *(const float4*)&bemb[t * 8 + 4];
    half8 h;
    h[0] = (_Float16)v0.x; h[1] = (_Float16)v0.y; h[2] = (_Float16)v0.z; h[3] = (_Float16)v0.w;
    h[4] = (_Float16)v1.x; h[5] = (_Float16)v1.y; h[6] = (_Float16)v1.z; h[7] = (_Float16)v1.w;
    sB[t] = h;
  }
  __syncthreads();
  int lane = threadIdx.x & 63;
  int quad = lane >> 4;
  int l15 = lane & 15;
  int c8 = l15 * 8;  // 8 halves = 16B
  int wid = blockIdx.x * (blockDim.x >> 6) + (threadIdx.x >> 6);
  int nw = gridDim.x * (blockDim.x >> 6);
  for (int i = wid; i < N_NODES; i += nw) {
    f32x8 ac[2];
    ac[0] = (f32x8)(0.f); ac[1] = (f32x8)(0.f);
    int e0 = row_ptr[i], e1 = row_ptr[i + 1];
    int j = e0 + quad;
#define EDGE(u, jj)                                                          \
    {                                                                        \
      int2 ed = csr2[jj];                                                    \
      half8 xr = *(const half8*)&x16[(size_t)ed.x * D + c8];                 \
      int p = ed.y;                                                          \
      half8 b0 = sB[(p & 15) * 16 + l15];                                    \
      half8 b1 = sB[256 + ((p >> 4) & 15) * 16 + l15];                       \
      half8 b2 = sB[512 + (p >> 8) * 16 + l15];                              \
      f32x8 m = __builtin_convertvector(xr, f32x8) +                         \
                __builtin_convertvector(b0, f32x8) +                         \
                __builtin_convertvector(b1, f32x8) +                         \
                __builtin_convertvector(b2, f32x8);                          \
      _Pragma("unroll")                                                      \
      for (int tt = 0; tt < 8; ++tt) m[tt] = fmaxf(m[tt], 0.f);              \
      ac[u] += m;                                                            \
    }
    for (; j + 4 < e1; j += 8) { EDGE(0, j) EDGE(1, j + 4) }
    for (; j < e1; j += 4) EDGE(0, j)
#undef EDGE
    f32x8 acc = ac[0] + ac[1];
#pragma unroll
    for (int tt = 0; tt < 8; ++tt) {
      acc[tt] += __shfl_xor(acc[tt], 16);
      acc[tt] += __shfl_xor(acc[tt], 32);
    }
    if (quad == 0) {
      half8 sr = *(const half8*)&x16[(size_t)i * D + c8];
      f32x8 o = __builtin_convertvector(sr, f32x8) + acc;
      *(half8*)&out[(size_t)i * D + c8] = __builtin_convertvector(o, half8);
    }
  }
}

// fused GINE nn: out = relu(A@W1+b1)@W2+b2 ; fp16 MFMA, W staged in LDS.
// 128-row tile, 4 waves (32 rows each = 2 x 16-row fragments).
__global__ __launch_bounds__(256) void k_conv(
    const _Float16* __restrict__ A,
    const _Float16* __restrict__ W1f, const float* __restrict__ b1,
    const _Float16* __restrict__ W2f, const float* __restrict__ b2,
    float* __restrict__ O32, _Float16* __restrict__ O16, int out_half) {
  __shared__ _Float16 sW[2048 * 8];     // 32 KB fragment-linear weights
  __shared__ _Float16 sI[128 * 136];    // 34 KB intermediate tile
  int tid = threadIdx.x, w = tid >> 6, lane = tid & 63;
  int m0 = blockIdx.x * 128;
  int col16 = lane & 15, q = lane >> 4;
  // stage W1
  for (int t = tid; t < 2048; t += 256)
    *(float4*)&sW[t * 8] = *(const float4*)&W1f[(size_t)t * 8];
  // A fragments (fp16 direct)
  half8 afr[2][4];
#pragma unroll
  for (int f = 0; f < 2; ++f) {
    int row = m0 + w * 32 + f * 16 + col16;
    if (row >= N_NODES) row = N_NODES - 1;
    const _Float16* Ar = A + (size_t)row * D + q * 8;
#pragma unroll
    for (int kk = 0; kk < 4; ++kk) afr[f][kk] = *(const half8*)(Ar + kk * 32);
  }
  __syncthreads();
  // layer 1 -> sI (bias + relu, fp16)
#pragma unroll
  for (int n0 = 0; n0 < 8; ++n0) {
    f32x4 a0 = {0.f, 0.f, 0.f, 0.f}, a1 = {0.f, 0.f, 0.f, 0.f};
#pragma unroll
    for (int kk = 0; kk < 4; ++kk) {
      half8 b = *(const half8*)&sW[((n0 * 4 + kk) * 64 + lane) * 8];
      a0 = __builtin_amdgcn_mfma_f32_16x16x32_f16(afr[0][kk], b, a0, 0, 0, 0);
      a1 = __builtin_amdgcn_mfma_f32_16x16x32_f16(afr[1][kk], b, a1, 0, 0, 0);
    }
    float bb = b1[n0 * 16 + col16];
#pragma unroll
    for (int r = 0; r < 4; ++r) {
      sI[(w * 32 + q * 4 + r) * 136 + n0 * 16 + col16] = (_Float16)fmaxf(a0[r] + bb, 0.f);
      sI[(w * 32 + 16 + q * 4 + r) * 136 + n0 * 16 + col16] = (_Float16)fmaxf(a1[r] + bb, 0.f);
    }
  }
  __syncthreads();
  // stage W2 (overwrite sW) + load layer-2 A fragments from sI
  for (int t = tid; t < 2048; t += 256)
    *(float4*)&sW[t * 8] = *(const float4*)&W2f[(size_t)t * 8];
  half8 a2[2][4];
#pragma unroll
  for (int f = 0; f < 2; ++f) {
    const _Float16* tr = &sI[(w * 32 + f * 16 + col16) * 136 + q * 8];
#pragma unroll
    for (int kk = 0; kk < 4; ++kk) a2[f][kk] = *(const half8*)(tr + kk * 32);
  }
  __syncthreads();
  // layer 2 (no relu)
#pragma unroll
  for (int n0 = 0; n0 < 8; ++n0) {
    f32x4 a0 = {0.f, 0.f, 0.f, 0.f}, a1 = {0.f, 0.f, 0.f, 0.f};
#pragma unroll
    for (int kk = 0; kk < 4; ++kk) {
      half8 b = *(const half8*)&sW[((n0 * 4 + kk) * 64 + lane) * 8];
      a0 = __builtin_amdgcn_mfma_f32_16x16x32_f16(a2[0][kk], b, a0, 0, 0, 0);
      a1 = __builtin_amdgcn_mfma_f32_16x16x32_f16(a2[1][kk], b, a1, 0, 0, 0);
    }
    int col = n0 * 16 + col16;
    float bb = b2[col];
#pragma unroll
    for (int r = 0; r < 4; ++r) {
      int r0 = m0 + w * 32 + q * 4 + r;
      int r1 = r0 + 16;
      if (r0 < N_NODES) {
        float v = a0[r] + bb;
        if (out_half) O16[(size_t)r0 * D + col] = (_Float16)v;
        else O32[(size_t)r0 * D + col] = v;
      }
      if (r1 < N_NODES) {
        float v = a1[r] + bb;
        if (out_half) O16[(size_t)r1 * D + col] = (_Float16)v;
        else O32[(size_t)r1 * D + col] = v;
      }
    }
  }
}

// mean-pool per graph + rdkit -> hcat16[G][352] fp16 (zero-padded 328..351)
__global__ __launch_bounds__(256) void k_pool(
    const float* __restrict__ x, const int* __restrict__ batch,
    const float* __restrict__ rdkit, _Float16* __restrict__ hcat) {
  int g = blockIdx.x * 4 + (threadIdx.x >> 6);
  if (g >= N_GRAPH) return;
  int lane = threadIdx.x & 63;
  int lo = lbound(batch, N_NODES, g);
  int hi = lbound(batch, N_NODES, g + 1);
  float a0 = 0.f, a1 = 0.f;
  for (int i = lo; i < hi; ++i) {
    float2 v = *(const float2*)&x[(size_t)i * D + lane * 2];
    a0 += v.x; a1 += v.y;
  }
  float inv = 1.f / fmaxf((float)(hi - lo), 1.f);
  hcat[(size_t)g * 352 + lane * 2] = (_Float16)(a0 * inv);
  hcat[(size_t)g * 352 + lane * 2 + 1] = (_Float16)(a1 * inv);
  for (int r = lane; r < RD; r += 64)
    hcat[(size_t)g * 352 + D + r] = (_Float16)rdkit[g * RD + r];
  if (lane < 24) hcat[(size_t)g * 352 + 328 + lane] = (_Float16)0.f;
}

// h1 = relu(hcat16[1024,352] @ W1t + b) -> fp16 [1024][512]
// wave = (mtile, ngroup of 64 cols): 64 x 8 = 512 waves (128 blocks).
__global__ __launch_bounds__(256) void k_mlp1(
    const _Float16* __restrict__ A, const _Float16* __restrict__ W1f,
    const float* __restrict__ B, _Float16* __restrict__ O) {
  int w = threadIdx.x >> 6, lane = threadIdx.x & 63;
  int gid = blockIdx.x * 4 + w;
  int mt = gid >> 3, ng = gid & 7;
  int col16 = lane & 15, q = lane >> 4;
  const _Float16* Ar = A + (size_t)(mt * 16 + col16) * 352 + q * 8;
  half8 afr[11];
#pragma unroll
  for (int kk = 0; kk < 11; ++kk) afr[kk] = *(const half8*)(Ar + kk * 32);
  f32x4 acc[4];
#pragma unroll
  for (int u = 0; u < 4; ++u) acc[u] = (f32x4){0.f, 0.f, 0.f, 0.f};
#pragma unroll
  for (int kk = 0; kk < 11; ++kk) {
#pragma unroll
    for (int u = 0; u < 4; ++u) {
      int n0 = ng * 4 + u;
      half8 b = *(const half8*)&W1f[(size_t)((n0 * 11 + kk) * 64 + lane) * 8];
      acc[u] = __builtin_amdgcn_mfma_f32_16x16x32_f16(afr[kk], b, acc[u], 0, 0, 0);
    }
  }
#pragma unroll
  for (int u = 0; u < 4; ++u) {
    int col = (ng * 4 + u) * 16 + col16;
    float bb = B[col];
#pragma unroll
    for (int r = 0; r < 4; ++r) {
      int row = mt * 16 + q * 4 + r;
      O[(size_t)row * 512 + col] = (_Float16)fmaxf(acc[u][r] + bb, 0.f);
    }
  }
}

// fused: h2 = relu(h1@W2+b2); out = h2@W3 + b3. Block = 1 mtile, 4 waves x 64 cols.
__global__ __launch_bounds__(256) void k_mlp23(
    const _Float16* __restrict__ A, const _Float16* __restrict__ W2f,
    const float* __restrict__ B2, const float* __restrict__ W3,
    const float* __restrict__ B3, float* __restrict__ out) {
  __shared__ float sRed[4][16];
  int w = threadIdx.x >> 6, lane = threadIdx.x & 63;
  int m0 = blockIdx.x * 16;
  int col16 = lane & 15, q = lane >> 4;
  const _Float16* Ar = A + (size_t)(m0 + col16) * 512 + q * 8;
  half8 afr[16];
#pragma unroll
  for (int kk = 0; kk < 16; ++kk) afr[kk] = *(const half8*)(Ar + kk * 32);
  f32x4 acc[4];
#pragma unroll
  for (int u = 0; u < 4; ++u) acc[u] = (f32x4){0.f, 0.f, 0.f, 0.f};
#pragma unroll
  for (int kk = 0; kk < 16; ++kk) {
#pragma unroll
    for (int u = 0; u < 4; ++u) {
      int n0 = w * 4 + u;
      half8 b = *(const half8*)&W2f[(size_t)((n0 * 16 + kk) * 64 + lane) * 8];
      acc[u] = __builtin_amdgcn_mfma_f32_16x16x32_f16(afr[kk], b, acc[u], 0, 0, 0);
    }
  }
  float p[4] = {0.f, 0.f, 0.f, 0.f};
#pragma unroll
  for (int u = 0; u < 4; ++u) {
    int col = (w * 4 + u) * 16 + col16;
    float bb = B2[col], w3 = W3[col];
#pragma unroll
    for (int r = 0; r < 4; ++r) p[r] += fmaxf(acc[u][r] + bb, 0.f) * w3;
  }
#pragma unroll
  for (int r = 0; r < 4; ++r) {
    p[r] += __shfl_xor(p[r], 1);
    p[r] += __shfl_xor(p[r], 2);
    p[r] += __shfl_xor(p[r], 4);
    p[r] += __shfl_xor(p[r], 8);
  }
  if (col16 == 0) {
#pragma unroll
    for (int r = 0; r < 4; ++r) sRed[w][q * 4 + r] = p[r];
  }
  __syncthreads();
  if (threadIdx.x < 16) {
    float s = sRed[0][threadIdx.x] + sRed[1][threadIdx.x] +
              sRed[2][threadIdx.x] + sRed[3][threadIdx.x];
    out[m0 + threadIdx.x] = s + B3[0];
  }
}

extern "C" void kernel_launch(void* const* d_in, const int* in_sizes, int n_in,
                              void* d_out, int out_size, void* d_ws, size_t ws_size,
                              hipStream_t stream) {
  const int* x_feat = (const int*)d_in[0];
  const int* ei = (const int*)d_in[1];
  const int* bondf = (const int*)d_in[2];
  const int* batch = (const int*)d_in[3];
  const float* rdkit = (const float*)d_in[4];
  const float* atom_emb = (const float*)d_in[5];
  const float* bond_emb = (const float*)d_in[6];
  const float* c1w1 = (const float*)d_in[7];
  const float* c1b1 = (const float*)d_in[8];
  const float* c1w2 = (const float*)d_in[9];
  const float* c1b2 = (const float*)d_in[10];
  const float* c2w1 = (const float*)d_in[11];
  const float* c2b1 = (const float*)d_in[12];
  const float* c2w2 = (const float*)d_in[13];
  const float* c2b2 = (const float*)d_in[14];
  const float* mw1 = (const float*)d_in[15];
  const float* mb1 = (const float*)d_in[16];
  const float* mw2 = (const float*)d_in[17];
  const float* mb2 = (const float*)d_in[18];
  const float* mw3 = (const float*)d_in[19];
  const float* mb3 = (const float*)d_in[20];
  float* out = (float*)d_out;

  char* ws = (char*)d_ws;
  size_t off = 0;
  auto alloc = [&](size_t bytes) {
    void* p = ws + off;
    off += (bytes + 255) & ~(size_t)255;
    return p;
  };
  _Float16* x16a = (_Float16*)alloc((size_t)N_NODES * D * 2);
  _Float16* x16b = (_Float16*)alloc((size_t)N_NODES * D * 2);
  _Float16* h16 = (_Float16*)alloc((size_t)N_NODES * D * 2);
  float* x2 = (float*)alloc((size_t)N_NODES * D * 4);
  int* deg = (int*)alloc((size_t)N_NODES * 4);
  int* cursor = (int*)alloc((size_t)N_NODES * 4);
  int* row_ptr = (int*)alloc((size_t)(N_NODES + 1) * 4);
  int* bsum = (int*)alloc(64 * 4);
  int2* csr2 = (int2*)alloc((size_t)N_EDGES * 8);
  _Float16* hcat16 = (_Float16*)alloc((size_t)N_GRAPH * 352 * 2);
  _Float16* h1buf = (_Float16*)alloc((size_t)N_GRAPH * 512 * 2);
  _Float16* cWf = (_Float16*)alloc((size_t)4 * 2048 * 8 * 2);
  _Float16* W1f = (_Float16*)alloc((size_t)352 * 64 * 8 * 2);
  _Float16* W2f = (_Float16*)alloc((size_t)256 * 64 * 8 * 2);

  k_prep<<<256, 256, 0, stream>>>(c1w1, c1w2, c2w1, c2w2, mw1, mw2,
                                  cWf, W1f, W2f, deg);
  k_atom_count<<<6250 + 2500, 256, 0, stream>>>(x_feat, atom_emb, x16a, ei, deg);

  int nb = (N_NODES + 1023) / 1024;
  k_scan_blocks<<<nb, 1024, 0, stream>>>(deg, row_ptr, bsum);
  k_scan_bsums<<<1, 64, 0, stream>>>(bsum, nb, row_ptr);
  k_scan_add<<<nb, 1024, 0, stream>>>(row_ptr, cursor, bsum);
  k_fill<<<(N_EDGES + 255) / 256, 256, 0, stream>>>(ei, bondf, cursor, csr2);

  int ctiles = (N_NODES + 127) / 128;  // 391
  // conv1
  k_agg<<<2048, 256, 0, stream>>>(x16a, row_ptr, csr2, bond_emb, h16);
  k_conv<<<ctiles, 256, 0, stream>>>(h16, cWf + 0 * 16384, c1b1,
                                     cWf + 1 * 16384, c1b2, nullptr, x16b, 1);
  // conv2
  k_agg<<<2048, 256, 0, stream>>>(x16b, row_ptr, csr2, bond_emb, h16);
  k_conv<<<ctiles, 256, 0, stream>>>(h16, cWf + 2 * 16384, c2b1,
                                     cWf + 3 * 16384, c2b2, x2, nullptr, 0);

  // pool + head MLP (MFMA fp16)
  k_pool<<<N_GRAPH / 4, 256, 0, stream>>>(x2, batch, rdkit, hcat16);
  k_mlp1<<<128, 256, 0, stream>>>(hcat16, W1f, mb1, h1buf);
  k_mlp23<<<64, 256, 0, stream>>>(h1buf, W2f, mb2, mw3, mb3, out);

  (void)in_sizes; (void)n_in; (void)out_size; (void)ws_size;
}

// Round 8
// 342.519 us; speedup vs baseline: 1.9965x; 1.0354x over previous
//
#include <hip/hip_runtime.h>

#define N_NODES 50000
#define N_EDGES 640000
#define N_GRAPH 1024
#define D 128
#define RD 200

typedef __attribute__((ext_vector_type(4))) float f32x4;
typedef __attribute__((ext_vector_type(8))) float f32x8;
typedef __attribute__((ext_vector_type(2))) _Float16 half2v;
typedef __attribute__((ext_vector_type(4))) _Float16 half4;
typedef __attribute__((ext_vector_type(8))) _Float16 half8;

static __device__ __forceinline__ int lbound(const int* a, int n, int v) {
  int lo = 0, hi = n;
  while (lo < hi) { int m = (lo + hi) >> 1; if (a[m] < v) lo = m + 1; else hi = m; }
  return lo;
}

// ---- prep: all weights -> fp16 MFMA-fragment-linear order ----
__global__ void k_prep(const float* __restrict__ w0, const float* __restrict__ w1,
                       const float* __restrict__ w2, const float* __restrict__ w3,
                       const float* __restrict__ mw1, const float* __restrict__ mw2,
                       _Float16* __restrict__ cWf,   // [4][32*64*8]
                       _Float16* __restrict__ W1f,   // [352*64*8]
                       _Float16* __restrict__ W2f) { // [256*64*8]
  int t = blockIdx.x * 256 + threadIdx.x;
  if (t < 8192) {
    int mat = t >> 11, r = t & 2047;
    int frag = r >> 6, lane = r & 63;
    int n0 = frag >> 2, kk = frag & 3;
    int n = n0 * 16 + (lane & 15);
    int kb = (lane >> 4) * 8 + kk * 32;
    const float* W = (mat == 0) ? w0 : (mat == 1) ? w1 : (mat == 2) ? w2 : w3;
    half8 o;
#pragma unroll
    for (int j = 0; j < 8; ++j) o[j] = (_Float16)W[(kb + j) * D + n];
    *(half8*)&cWf[((size_t)mat * 2048 + r) * 8] = o;
  } else if (t < 8192 + 22528) {
    int u = t - 8192;
    int frag = u >> 6, lane = u & 63;
    int n0 = frag / 11, kk = frag % 11;
    int n = n0 * 16 + (lane & 15);
    int kb = (lane >> 4) * 8 + kk * 32;
    half8 o;
#pragma unroll
    for (int j = 0; j < 8; ++j) {
      int k = kb + j;
      o[j] = (k < 328) ? (_Float16)mw1[k * 512 + n] : (_Float16)0.f;
    }
    *(half8*)&W1f[(size_t)u * 8] = o;
  } else if (t < 8192 + 22528 + 16384) {
    int u = t - 8192 - 22528;
    int frag = u >> 6, lane = u & 63;
    int n0 = frag >> 4, kk = frag & 15;
    int n = n0 * 16 + (lane & 15);
    int kb = (lane >> 4) * 8 + kk * 32;
    half8 o;
#pragma unroll
    for (int j = 0; j < 8; ++j) o[j] = (_Float16)mw2[(kb + j) * 256 + n];
    *(half8*)&W2f[(size_t)u * 8] = o;
  }
}

// fused: atom encoder (fp16 out) + edge degree count
__global__ void k_atom_count(const int* __restrict__ xf, const float* __restrict__ emb,
                             _Float16* __restrict__ x16,
                             const int* __restrict__ ei, int* __restrict__ deg) {
  if (blockIdx.x < 6250) {
    int t = blockIdx.x * 256 + threadIdx.x;  // exactly 50000*32
    int node = t >> 5, c = (t & 31) << 2;
    float a0 = 0.f, a1 = 0.f, a2 = 0.f, a3 = 0.f;
#pragma unroll
    for (int f = 0; f < 9; ++f) {
      int v = xf[node * 9 + f];
      float4 e4 = *(const float4*)&emb[(f * 64 + v) * D + c];
      a0 += e4.x; a1 += e4.y; a2 += e4.z; a3 += e4.w;
    }
    half4 o;
    o.x = (_Float16)a0; o.y = (_Float16)a1; o.z = (_Float16)a2; o.w = (_Float16)a3;
    *(half4*)&x16[(size_t)node * D + c] = o;
  } else {
    int e = (blockIdx.x - 6250) * 256 + threadIdx.x;
    if (e < N_EDGES) atomicAdd(&deg[ei[N_EDGES + e]], 1);
  }
}

__global__ void k_scan_blocks(const int* __restrict__ deg, int* __restrict__ excl,
                              int* __restrict__ bsum) {
  __shared__ int sd[1024];
  int i = blockIdx.x * 1024 + threadIdx.x;
  int v = (i < N_NODES) ? deg[i] : 0;
  sd[threadIdx.x] = v;
  __syncthreads();
  for (int off = 1; off < 1024; off <<= 1) {
    int t = (threadIdx.x >= (unsigned)off) ? sd[threadIdx.x - off] : 0;
    __syncthreads();
    sd[threadIdx.x] += t;
    __syncthreads();
  }
  if (i < N_NODES) excl[i] = sd[threadIdx.x] - v;
  if (threadIdx.x == 1023) bsum[blockIdx.x] = sd[1023];
}

// merged: add block-prefix of bsum; row_ptr[N] = E (constant)
__global__ void k_scan_add(int* __restrict__ row_ptr, int* __restrict__ cursor,
                           const int* __restrict__ bsum) {
  int off = 0;
  for (int b = 0; b < blockIdx.x; ++b) off += bsum[b];
  int i = blockIdx.x * 1024 + threadIdx.x;
  if (i < N_NODES) {
    int r = row_ptr[i] + off;
    row_ptr[i] = r;
    cursor[i] = r;
  }
  if (blockIdx.x == 0 && threadIdx.x == 0) row_ptr[N_NODES] = N_EDGES;
}

__global__ void k_fill(const int* __restrict__ ei, const int* __restrict__ bondf,
                       int* __restrict__ cursor, int2* __restrict__ csr2) {
  int e = blockIdx.x * 256 + threadIdx.x;
  if (e >= N_EDGES) return;
  int s = ei[e], d = ei[N_EDGES + e];
  int f0 = bondf[e * 3], f1 = bondf[e * 3 + 1], f2 = bondf[e * 3 + 2];
  int pos = atomicAdd(&cursor[d], 1);
  int2 v; v.x = s; v.y = f0 | (f1 << 4) | (f2 << 8);
  csr2[pos] = v;
}

// out[i] = x[i] + sum_j relu(x[src] + bond_emb_sum)
// fp16 packed message math (v_pk_add_f16), fp32 accumulate.
__global__ __launch_bounds__(256) void k_agg(
    const _Float16* __restrict__ x16, const int* __restrict__ row_ptr,
    const int2* __restrict__ csr2, const float* __restrict__ bemb,
    _Float16* __restrict__ out) {
  __shared__ half8 sB[48 * 16];  // 12 KB fp16 bond table
  for (int t = threadIdx.x; t < 768; t += blockDim.x) {
    float4 v0 = *(const float4*)&bemb[t * 8];
    float4 v1 = *(const float4*)&bemb[t * 8 + 4];
    half8 h;
    h[0] = (_Float16)v0.x; h[1] = (_Float16)v0.y; h[2] = (_Float16)v0.z; h[3] = (_Float16)v0.w;
    h[4] = (_Float16)v1.x; h[5] = (_Float16)v1.y; h[6] = (_Float16)v1.z; h[7] = (_Float16)v1.w;
    sB[t] = h;
  }
  __syncthreads();
  int lane = threadIdx.x & 63;
  int quad = lane >> 4;
  int l15 = lane & 15;
  int c8 = l15 * 8;  // 8 halves = 16B
  int wid = blockIdx.x * (blockDim.x >> 6) + (threadIdx.x >> 6);
  int nw = gridDim.x * (blockDim.x >> 6);
  for (int i = wid; i < N_NODES; i += nw) {
    f32x8 ac[2];
    ac[0] = (f32x8)(0.f); ac[1] = (f32x8)(0.f);
    int e0 = row_ptr[i], e1 = row_ptr[i + 1];
    int j = e0 + quad;
#define EDGE(u, jj)                                                          \
    {                                                                        \
      int2 ed = csr2[jj];                                                    \
      half8 xr = *(const half8*)&x16[(size_t)ed.x * D + c8];                 \
      int p = ed.y;                                                          \
      half8 m16 = (xr + sB[(p & 15) * 16 + l15]) +                           \
                  (sB[256 + ((p >> 4) & 15) * 16 + l15] +                    \
                   sB[512 + (p >> 8) * 16 + l15]);                           \
      f32x8 m = __builtin_convertvector(m16, f32x8);                         \
      _Pragma("unroll")                                                      \
      for (int tt = 0; tt < 8; ++tt) ac[u][tt] += fmaxf(m[tt], 0.f);         \
    }
    for (; j + 4 < e1; j += 8) { EDGE(0, j) EDGE(1, j + 4) }
    for (; j < e1; j += 4) EDGE(0, j)
#undef EDGE
    f32x8 acc = ac[0] + ac[1];
#pragma unroll
    for (int tt = 0; tt < 8; ++tt) {
      acc[tt] += __shfl_xor(acc[tt], 16);
      acc[tt] += __shfl_xor(acc[tt], 32);
    }
    if (quad == 0) {
      half8 sr = *(const half8*)&x16[(size_t)i * D + c8];
      f32x8 o = __builtin_convertvector(sr, f32x8) + acc;
      *(half8*)&out[(size_t)i * D + c8] = __builtin_convertvector(o, half8);
    }
  }
}

// fused GINE nn: out = relu(A@W1+b1)@W2+b2 ; fp16 MFMA, W staged in LDS.
__global__ __launch_bounds__(256) void k_conv(
    const _Float16* __restrict__ A,
    const _Float16* __restrict__ W1f, const float* __restrict__ b1,
    const _Float16* __restrict__ W2f, const float* __restrict__ b2,
    _Float16* __restrict__ O16) {
  __shared__ _Float16 sW[2048 * 8];     // 32 KB fragment-linear weights
  __shared__ _Float16 sI[128 * 136];    // 34 KB intermediate tile
  int tid = threadIdx.x, w = tid >> 6, lane = tid & 63;
  int m0 = blockIdx.x * 128;
  int col16 = lane & 15, q = lane >> 4;
  for (int t = tid; t < 2048; t += 256)
    *(float4*)&sW[t * 8] = *(const float4*)&W1f[(size_t)t * 8];
  half8 afr[2][4];
#pragma unroll
  for (int f = 0; f < 2; ++f) {
    int row = m0 + w * 32 + f * 16 + col16;
    if (row >= N_NODES) row = N_NODES - 1;
    const _Float16* Ar = A + (size_t)row * D + q * 8;
#pragma unroll
    for (int kk = 0; kk < 4; ++kk) afr[f][kk] = *(const half8*)(Ar + kk * 32);
  }
  __syncthreads();
#pragma unroll
  for (int n0 = 0; n0 < 8; ++n0) {
    f32x4 a0 = {0.f, 0.f, 0.f, 0.f}, a1 = {0.f, 0.f, 0.f, 0.f};
#pragma unroll
    for (int kk = 0; kk < 4; ++kk) {
      half8 b = *(const half8*)&sW[((n0 * 4 + kk) * 64 + lane) * 8];
      a0 = __builtin_amdgcn_mfma_f32_16x16x32_f16(afr[0][kk], b, a0, 0, 0, 0);
      a1 = __builtin_amdgcn_mfma_f32_16x16x32_f16(afr[1][kk], b, a1, 0, 0, 0);
    }
    float bb = b1[n0 * 16 + col16];
#pragma unroll
    for (int r = 0; r < 4; ++r) {
      sI[(w * 32 + q * 4 + r) * 136 + n0 * 16 + col16] = (_Float16)fmaxf(a0[r] + bb, 0.f);
      sI[(w * 32 + 16 + q * 4 + r) * 136 + n0 * 16 + col16] = (_Float16)fmaxf(a1[r] + bb, 0.f);
    }
  }
  __syncthreads();
  for (int t = tid; t < 2048; t += 256)
    *(float4*)&sW[t * 8] = *(const float4*)&W2f[(size_t)t * 8];
  half8 a2[2][4];
#pragma unroll
  for (int f = 0; f < 2; ++f) {
    const _Float16* tr = &sI[(w * 32 + f * 16 + col16) * 136 + q * 8];
#pragma unroll
    for (int kk = 0; kk < 4; ++kk) a2[f][kk] = *(const half8*)(tr + kk * 32);
  }
  __syncthreads();
#pragma unroll
  for (int n0 = 0; n0 < 8; ++n0) {
    f32x4 a0 = {0.f, 0.f, 0.f, 0.f}, a1 = {0.f, 0.f, 0.f, 0.f};
#pragma unroll
    for (int kk = 0; kk < 4; ++kk) {
      half8 b = *(const half8*)&sW[((n0 * 4 + kk) * 64 + lane) * 8];
      a0 = __builtin_amdgcn_mfma_f32_16x16x32_f16(a2[0][kk], b, a0, 0, 0, 0);
      a1 = __builtin_amdgcn_mfma_f32_16x16x32_f16(a2[1][kk], b, a1, 0, 0, 0);
    }
    int col = n0 * 16 + col16;
    float bb = b2[col];
#pragma unroll
    for (int r = 0; r < 4; ++r) {
      int r0 = m0 + w * 32 + q * 4 + r;
      int r1 = r0 + 16;
      if (r0 < N_NODES) O16[(size_t)r0 * D + col] = (_Float16)(a0[r] + bb);
      if (r1 < N_NODES) O16[(size_t)r1 * D + col] = (_Float16)(a1[r] + bb);
    }
  }
}

// mean-pool per graph (fp16 input) + rdkit -> hcat16[G][352]
__global__ __launch_bounds__(256) void k_pool(
    const _Float16* __restrict__ x, const int* __restrict__ batch,
    const float* __restrict__ rdkit, _Float16* __restrict__ hcat) {
  int g = blockIdx.x * 4 + (threadIdx.x >> 6);
  if (g >= N_GRAPH) return;
  int lane = threadIdx.x & 63;
  int lo = lbound(batch, N_NODES, g);
  int hi = lbound(batch, N_NODES, g + 1);
  float a0 = 0.f, a1 = 0.f;
  for (int i = lo; i < hi; ++i) {
    half2v v = *(const half2v*)&x[(size_t)i * D + lane * 2];
    a0 += (float)v.x; a1 += (float)v.y;
  }
  float inv = 1.f / fmaxf((float)(hi - lo), 1.f);
  hcat[(size_t)g * 352 + lane * 2] = (_Float16)(a0 * inv);
  hcat[(size_t)g * 352 + lane * 2 + 1] = (_Float16)(a1 * inv);
  for (int r = lane; r < RD; r += 64)
    hcat[(size_t)g * 352 + D + r] = (_Float16)rdkit[g * RD + r];
  if (lane < 24) hcat[(size_t)g * 352 + 328 + lane] = (_Float16)0.f;
}

// h1 = relu(hcat16[1024,352] @ W1t + b) -> fp16 [1024][512]
__global__ __launch_bounds__(256) void k_mlp1(
    const _Float16* __restrict__ A, const _Float16* __restrict__ W1f,
    const float* __restrict__ B, _Float16* __restrict__ O) {
  int w = threadIdx.x >> 6, lane = threadIdx.x & 63;
  int gid = blockIdx.x * 4 + w;
  int mt = gid >> 3, ng = gid & 7;
  int col16 = lane & 15, q = lane >> 4;
  const _Float16* Ar = A + (size_t)(mt * 16 + col16) * 352 + q * 8;
  half8 afr[11];
#pragma unroll
  for (int kk = 0; kk < 11; ++kk) afr[kk] = *(const half8*)(Ar + kk * 32);
  f32x4 acc[4];
#pragma unroll
  for (int u = 0; u < 4; ++u) acc[u] = (f32x4){0.f, 0.f, 0.f, 0.f};
#pragma unroll
  for (int kk = 0; kk < 11; ++kk) {
#pragma unroll
    for (int u = 0; u < 4; ++u) {
      int n0 = ng * 4 + u;
      half8 b = *(const half8*)&W1f[(size_t)((n0 * 11 + kk) * 64 + lane) * 8];
      acc[u] = __builtin_amdgcn_mfma_f32_16x16x32_f16(afr[kk], b, acc[u], 0, 0, 0);
    }
  }
#pragma unroll
  for (int u = 0; u < 4; ++u) {
    int col = (ng * 4 + u) * 16 + col16;
    float bb = B[col];
#pragma unroll
    for (int r = 0; r < 4; ++r) {
      int row = mt * 16 + q * 4 + r;
      O[(size_t)row * 512 + col] = (_Float16)fmaxf(acc[u][r] + bb, 0.f);
    }
  }
}

// fused: h2 = relu(h1@W2+b2); out = h2@W3 + b3
__global__ __launch_bounds__(256) void k_mlp23(
    const _Float16* __restrict__ A, const _Float16* __restrict__ W2f,
    const float* __restrict__ B2, const float* __restrict__ W3,
    const float* __restrict__ B3, float* __restrict__ out) {
  __shared__ float sRed[4][16];
  int w = threadIdx.x >> 6, lane = threadIdx.x & 63;
  int m0 = blockIdx.x * 16;
  int col16 = lane & 15, q = lane >> 4;
  const _Float16* Ar = A + (size_t)(m0 + col16) * 512 + q * 8;
  half8 afr[16];
#pragma unroll
  for (int kk = 0; kk < 16; ++kk) afr[kk] = *(const half8*)(Ar + kk * 32);
  f32x4 acc[4];
#pragma unroll
  for (int u = 0; u < 4; ++u) acc[u] = (f32x4){0.f, 0.f, 0.f, 0.f};
#pragma unroll
  for (int kk = 0; kk < 16; ++kk) {
#pragma unroll
    for (int u = 0; u < 4; ++u) {
      int n0 = w * 4 + u;
      half8 b = *(const half8*)&W2f[(size_t)((n0 * 16 + kk) * 64 + lane) * 8];
      acc[u] = __builtin_amdgcn_mfma_f32_16x16x32_f16(afr[kk], b, acc[u], 0, 0, 0);
    }
  }
  float p[4] = {0.f, 0.f, 0.f, 0.f};
#pragma unroll
  for (int u = 0; u < 4; ++u) {
    int col = (w * 4 + u) * 16 + col16;
    float bb = B2[col], w3 = W3[col];
#pragma unroll
    for (int r = 0; r < 4; ++r) p[r] += fmaxf(acc[u][r] + bb, 0.f) * w3;
  }
#pragma unroll
  for (int r = 0; r < 4; ++r) {
    p[r] += __shfl_xor(p[r], 1);
    p[r] += __shfl_xor(p[r], 2);
    p[r] += __shfl_xor(p[r], 4);
    p[r] += __shfl_xor(p[r], 8);
  }
  if (col16 == 0) {
#pragma unroll
    for (int r = 0; r < 4; ++r) sRed[w][q * 4 + r] = p[r];
  }
  __syncthreads();
  if (threadIdx.x < 16) {
    float s = sRed[0][threadIdx.x] + sRed[1][threadIdx.x] +
              sRed[2][threadIdx.x] + sRed[3][threadIdx.x];
    out[m0 + threadIdx.x] = s + B3[0];
  }
}

extern "C" void kernel_launch(void* const* d_in, const int* in_sizes, int n_in,
                              void* d_out, int out_size, void* d_ws, size_t ws_size,
                              hipStream_t stream) {
  const int* x_feat = (const int*)d_in[0];
  const int* ei = (const int*)d_in[1];
  const int* bondf = (const int*)d_in[2];
  const int* batch = (const int*)d_in[3];
  const float* rdkit = (const float*)d_in[4];
  const float* atom_emb = (const float*)d_in[5];
  const float* bond_emb = (const float*)d_in[6];
  const float* c1w1 = (const float*)d_in[7];
  const float* c1b1 = (const float*)d_in[8];
  const float* c1w2 = (const float*)d_in[9];
  const float* c1b2 = (const float*)d_in[10];
  const float* c2w1 = (const float*)d_in[11];
  const float* c2b1 = (const float*)d_in[12];
  const float* c2w2 = (const float*)d_in[13];
  const float* c2b2 = (const float*)d_in[14];
  const float* mw1 = (const float*)d_in[15];
  const float* mb1 = (const float*)d_in[16];
  const float* mw2 = (const float*)d_in[17];
  const float* mb2 = (const float*)d_in[18];
  const float* mw3 = (const float*)d_in[19];
  const float* mb3 = (const float*)d_in[20];
  float* out = (float*)d_out;

  char* ws = (char*)d_ws;
  size_t off = 0;
  auto alloc = [&](size_t bytes) {
    void* p = ws + off;
    off += (bytes + 255) & ~(size_t)255;
    return p;
  };
  _Float16* x16a = (_Float16*)alloc((size_t)N_NODES * D * 2);
  _Float16* x16b = (_Float16*)alloc((size_t)N_NODES * D * 2);
  _Float16* h16 = (_Float16*)alloc((size_t)N_NODES * D * 2);
  _Float16* x2_16 = (_Float16*)alloc((size_t)N_NODES * D * 2);
  int* deg = (int*)alloc((size_t)N_NODES * 4);
  int* cursor = (int*)alloc((size_t)N_NODES * 4);
  int* row_ptr = (int*)alloc((size_t)(N_NODES + 1) * 4);
  int* bsum = (int*)alloc(64 * 4);
  int2* csr2 = (int2*)alloc((size_t)N_EDGES * 8);
  _Float16* hcat16 = (_Float16*)alloc((size_t)N_GRAPH * 352 * 2);
  _Float16* h1buf = (_Float16*)alloc((size_t)N_GRAPH * 512 * 2);
  _Float16* cWf = (_Float16*)alloc((size_t)4 * 2048 * 8 * 2);
  _Float16* W1f = (_Float16*)alloc((size_t)352 * 64 * 8 * 2);
  _Float16* W2f = (_Float16*)alloc((size_t)256 * 64 * 8 * 2);

  hipMemsetAsync(deg, 0, (size_t)N_NODES * 4, stream);
  k_prep<<<256, 256, 0, stream>>>(c1w1, c1w2, c2w1, c2w2, mw1, mw2, cWf, W1f, W2f);
  k_atom_count<<<6250 + 2500, 256, 0, stream>>>(x_feat, atom_emb, x16a, ei, deg);

  int nb = (N_NODES + 1023) / 1024;
  k_scan_blocks<<<nb, 1024, 0, stream>>>(deg, row_ptr, bsum);
  k_scan_add<<<nb, 1024, 0, stream>>>(row_ptr, cursor, bsum);
  k_fill<<<(N_EDGES + 255) / 256, 256, 0, stream>>>(ei, bondf, cursor, csr2);

  int ctiles = (N_NODES + 127) / 128;  // 391
  // conv1
  k_agg<<<2048, 256, 0, stream>>>(x16a, row_ptr, csr2, bond_emb, h16);
  k_conv<<<ctiles, 256, 0, stream>>>(h16, cWf + 0 * 16384, c1b1,
                                     cWf + 1 * 16384, c1b2, x16b);
  // conv2
  k_agg<<<2048, 256, 0, stream>>>(x16b, row_ptr, csr2, bond_emb, h16);
  k_conv<<<ctiles, 256, 0, stream>>>(h16, cWf + 2 * 16384, c2b1,
                                     cWf + 3 * 16384, c2b2, x2_16);

  // pool + head MLP (MFMA fp16)
  k_pool<<<N_GRAPH / 4, 256, 0, stream>>>(x2_16, batch, rdkit, hcat16);
  k_mlp1<<<128, 256, 0, stream>>>(hcat16, W1f, mb1, h1buf);
  k_mlp23<<<64, 256, 0, stream>>>(h1buf, W2f, mb2, mw3, mb3, out);

  (void)in_sizes; (void)n_in; (void)out_size; (void)ws_size;
}